// Round 7
// baseline (258.849 us; speedup 1.0000x reference)
//
#include <hip/hip_runtime.h>
#include <hip/hip_bf16.h>

// Problem constants: B=2, S=2048, DIM=2048, H=16, KVH=8, D=128

typedef __attribute__((ext_vector_type(8))) short s16x8;   // 8 bf16 in 4 VGPRs
typedef __attribute__((ext_vector_type(4))) float f32x4;

typedef const __attribute__((address_space(1))) void* gas_t;
typedef __attribute__((address_space(3))) void* las_t;
#define GLL16(g, l) __builtin_amdgcn_global_load_lds((gas_t)(const void*)(g), (las_t)(void*)(l), 16, 0, 0)

static __device__ __forceinline__ unsigned short f2bf(float f) {
    union { float f; unsigned u; } v; v.f = f;
    unsigned r = v.u + 0x7FFF + ((v.u >> 16) & 1);   // RNE
    return (unsigned short)(r >> 16);
}
static __device__ __forceinline__ float bf2f(unsigned short h) {
    union { unsigned u; float f; } v; v.u = ((unsigned)h) << 16;
    return v.f;
}

// ---------------- f32 -> bf16 elementwise convert (x) ----------------
__global__ __launch_bounds__(256) void k_convert_x(const float* __restrict__ x,
                                                   unsigned short* __restrict__ xb, int n) {
    int i = (blockIdx.x * 256 + threadIdx.x) * 8;
    if (i >= n) return;
    float4 a = *(const float4*)(x + i);
    float4 b = *(const float4*)(x + i + 4);
    s16x8 o;
    o[0] = (short)f2bf(a.x); o[1] = (short)f2bf(a.y); o[2] = (short)f2bf(a.z); o[3] = (short)f2bf(a.w);
    o[4] = (short)f2bf(b.x); o[5] = (short)f2bf(b.y); o[6] = (short)f2bf(b.z); o[7] = (short)f2bf(b.w);
    *(s16x8*)(xb + i) = o;
}

// ---------------- weight transpose f32 (K x N) -> bf16 (N x K) ----------------
__global__ __launch_bounds__(256) void k_transpose_w(const float* __restrict__ src,
                                                     unsigned short* __restrict__ dst,
                                                     int K, int N, int nbase, int dstld) {
    __shared__ float t[32][33];
    int k0 = blockIdx.x * 32, n0 = blockIdx.y * 32;
    int tx = threadIdx.x & 31, ty0 = threadIdx.x >> 5;
    for (int p = 0; p < 4; p++) {
        int ty = ty0 + p * 8;
        t[ty][tx] = src[(size_t)(k0 + ty) * N + n0 + tx];
    }
    __syncthreads();
    for (int p = 0; p < 4; p++) {
        int ty = ty0 + p * 8;
        dst[(size_t)(nbase + n0 + ty) * dstld + k0 + tx] = f2bf(t[tx][ty]);
    }
}

// ---------------- bf16 transpose: V (2048 x 128) -> Vt (128 x 2048), per (b,kvh) ----------------
__global__ __launch_bounds__(256) void k_transpose_v(const unsigned short* __restrict__ V,
                                                     unsigned short* __restrict__ Vt) {
    __shared__ unsigned short t[32][33];
    int s0 = blockIdx.x * 32, d0 = blockIdx.y * 32;
    size_t base = (size_t)blockIdx.z * 2048 * 128;
    int tx = threadIdx.x & 31, ty0 = threadIdx.x >> 5;
    for (int p = 0; p < 4; p++) {
        int ty = ty0 + p * 8;
        t[ty][tx] = V[base + (size_t)(s0 + ty) * 128 + d0 + tx];
    }
    __syncthreads();
    for (int p = 0; p < 4; p++) {
        int ty = ty0 + p * 8;
        Vt[base + (size_t)(d0 + ty) * 2048 + s0 + tx] = t[tx][ty];
    }
}

// ---------------- 8-phase 256x256 GEMM: C = A(MxK) * Bt(NxK)^T ----------------
template<int OUTF32>
__global__ __launch_bounds__(512, 2) void k_gemm256(const unsigned short* __restrict__ A,
                                                    const unsigned short* __restrict__ Bt,
                                                    void* __restrict__ Cout,
                                                    int M, int N, int K) {
    __shared__ unsigned short As[2][256 * 64];
    __shared__ unsigned short Bs[2][256 * 64];
    int tid = threadIdx.x, lane = tid & 63, wave = tid >> 6;
    int wm = wave >> 2, wn = wave & 3;
    int lr = lane & 15, lg = lane >> 4;
    int srow = wave * 8 + (lane >> 3);
    int scol = (((lane & 7) ^ (lane >> 3)) * 8);
    const unsigned short* Ag = A  + (size_t)(blockIdx.x * 256 + srow) * K + scol;
    const unsigned short* Bg = Bt + (size_t)(blockIdx.y * 256 + srow) * K + scol;
    int ldsoff = wave * 512;

    f32x4 acc[8][4] = {};
    int NK = K / 64;
    #pragma unroll
    for (int p = 0; p < 4; p++) {
        GLL16(Ag + (size_t)p * 64 * K, &As[0][p * 4096 + ldsoff]);
        GLL16(Bg + (size_t)p * 64 * K, &Bs[0][p * 4096 + ldsoff]);
    }
    for (int t = 0; t < NK; ++t) {
        int slot = t & 1, nslot = slot ^ 1;
        size_t kn = (size_t)(t + 1) * 64;
        bool more = (t + 1) < NK;
        if (more) {
            GLL16(Ag + kn, &As[nslot][ldsoff]);
            GLL16(Bg + kn, &Bs[nslot][ldsoff]);
            asm volatile("s_waitcnt vmcnt(2)" ::: "memory");
        } else {
            asm volatile("s_waitcnt vmcnt(0)" ::: "memory");
        }
        __builtin_amdgcn_s_barrier();
        asm volatile("" ::: "memory");
        s16x8 bf[4][2];
        #pragma unroll
        for (int n = 0; n < 4; n++)
            #pragma unroll
            for (int kk = 0; kk < 2; kk++)
                bf[n][kk] = *(const s16x8*)&Bs[slot][(wn * 64 + n * 16 + lr) * 64 +
                                                     ((kk * 32 + lg * 8) ^ ((lr & 7) << 3))];
        #pragma unroll
        for (int q = 0; q < 4; q++) {
            s16x8 af[2][2];
            #pragma unroll
            for (int mm = 0; mm < 2; mm++)
                #pragma unroll
                for (int kk = 0; kk < 2; kk++)
                    af[mm][kk] = *(const s16x8*)&As[slot][(wm * 128 + (q * 2 + mm) * 16 + lr) * 64 +
                                                          ((kk * 32 + lg * 8) ^ ((lr & 7) << 3))];
            if (more && q < 3) {
                GLL16(Ag + (size_t)(q + 1) * 64 * K + kn, &As[nslot][(q + 1) * 4096 + ldsoff]);
                GLL16(Bg + (size_t)(q + 1) * 64 * K + kn, &Bs[nslot][(q + 1) * 4096 + ldsoff]);
            }
            __builtin_amdgcn_s_barrier();
            __builtin_amdgcn_s_setprio(1);
            #pragma unroll
            for (int mm = 0; mm < 2; mm++)
                #pragma unroll
                for (int n = 0; n < 4; n++)
                    #pragma unroll
                    for (int kk = 0; kk < 2; kk++)
                        acc[q * 2 + mm][n] = __builtin_amdgcn_mfma_f32_16x16x32_bf16(
                            af[mm][kk], bf[n][kk], acc[q * 2 + mm][n], 0, 0, 0);
            __builtin_amdgcn_s_setprio(0);
            __builtin_amdgcn_s_barrier();
        }
    }
    int rbase = blockIdx.x * 256 + wm * 128;
    int cbase = blockIdx.y * 256 + wn * 64;
    #pragma unroll
    for (int am = 0; am < 8; am++)
        #pragma unroll
        for (int n = 0; n < 4; n++)
            #pragma unroll
            for (int r = 0; r < 4; r++) {
                int row = rbase + am * 16 + lg * 4 + r;
                int col = cbase + n * 16 + lr;
                float v = acc[am][n][r];
                if (OUTF32) ((float*)Cout)[(size_t)row * N + col] = v;
                else        ((unsigned short*)Cout)[(size_t)row * N + col] = f2bf(v);
            }
}

// ---------------- GEMM: 128x128 m97 structure (kept for gemm2, N=2048) ----------------
template<int OUTF32>
__global__ __launch_bounds__(256) void k_gemm_bt(const unsigned short* __restrict__ A,
                                                 const unsigned short* __restrict__ Bt,
                                                 void* __restrict__ Cout,
                                                 int M, int N, int K) {
    __shared__ unsigned short As[128 * 32];
    __shared__ unsigned short Bs[128 * 32];
    int tid = threadIdx.x;
    int lane = tid & 63;
    int wave = tid >> 6;
    int wm = wave >> 1, wn = wave & 1;
    int lr = lane & 15, lk = (lane >> 4) * 8;
    int srow = wave * 32 + (lane >> 2);
    int scol = (lane & 3) * 8;
    const unsigned short* Ag0 = A  + (size_t)(blockIdx.x * 128 + srow) * K + scol;
    const unsigned short* Ag1 = Ag0 + (size_t)16 * K;
    const unsigned short* Bg0 = Bt + (size_t)(blockIdx.y * 128 + srow) * K + scol;
    const unsigned short* Bg1 = Bg0 + (size_t)16 * K;
    unsigned short* Asw = &As[wave * 1024];
    unsigned short* Bsw = &Bs[wave * 1024];
    f32x4 acc[4][4] = {};
    for (int k0 = 0; k0 < K; k0 += 32) {
        __syncthreads();
        GLL16(Ag0 + k0, Asw);
        GLL16(Ag1 + k0, Asw + 512);
        GLL16(Bg0 + k0, Bsw);
        GLL16(Bg1 + k0, Bsw + 512);
        __syncthreads();
        s16x8 af[4], bfr[4];
        #pragma unroll
        for (int m = 0; m < 4; m++) af[m]  = *(const s16x8*)&As[(wm * 64 + m * 16 + lr) * 32 + lk];
        #pragma unroll
        for (int n = 0; n < 4; n++) bfr[n] = *(const s16x8*)&Bs[(wn * 64 + n * 16 + lr) * 32 + lk];
        #pragma unroll
        for (int m = 0; m < 4; m++)
            #pragma unroll
            for (int n = 0; n < 4; n++)
                acc[m][n] = __builtin_amdgcn_mfma_f32_16x16x32_bf16(af[m], bfr[n], acc[m][n], 0, 0, 0);
    }
    int rbase = blockIdx.x * 128 + wm * 64;
    int cbase = blockIdx.y * 128 + wn * 64;
    #pragma unroll
    for (int m = 0; m < 4; m++)
        #pragma unroll
        for (int n = 0; n < 4; n++)
            #pragma unroll
            for (int r = 0; r < 4; r++) {
                int row = rbase + m * 16 + (lane >> 4) * 4 + r;
                int col = cbase + n * 16 + lr;
                float v = acc[m][n][r];
                if (OUTF32) ((float*)Cout)[(size_t)row * N + col] = v;
                else        ((unsigned short*)Cout)[(size_t)row * N + col] = f2bf(v);
            }
}

// ---------------- fused RMSNorm + RoPE + head transpose ----------------
__global__ __launch_bounds__(256) void k_rms_rope(const unsigned short* __restrict__ qkv,
                                                  const float* __restrict__ qg,
                                                  const float* __restrict__ kg,
                                                  const float* __restrict__ cosc,
                                                  const float* __restrict__ sinc,
                                                  unsigned short* __restrict__ Qt,
                                                  unsigned short* __restrict__ Kt,
                                                  unsigned short* __restrict__ Vt) {
    int r = blockIdx.x;            // b*2048 + s
    int b = r >> 11;
    int s = r & 2047;
    int wave = threadIdx.x >> 6, lane = threadIdx.x & 63;
    const unsigned short* row = qkv + (size_t)r * 4096;
    float c  = cosc[s * 64 + lane];
    float sn = sinc[s * 64 + lane];
    for (int seg = wave; seg < 32; seg += 4) {
        int col0 = seg * 128;
        float e0 = bf2f(row[col0 + lane]);
        float e1 = bf2f(row[col0 + 64 + lane]);
        if (seg < 24) {
            float ss = e0 * e0 + e1 * e1;
            for (int m = 1; m < 64; m <<= 1) ss += __shfl_xor(ss, m, 64);
            float rn = rsqrtf(ss * (1.0f / 128.0f) + 1e-6f);
            const float* g = (seg < 16) ? qg : kg;
            float t0 = e0 * rn * g[lane];
            float t1 = e1 * rn * g[lane + 64];
            float o0 = t0 * c - t1 * sn;
            float o1 = t1 * c + t0 * sn;
            unsigned short* dst;
            if (seg < 16) dst = Qt + ((size_t)(b * 16 + seg) * 2048 + s) * 128;
            else          dst = Kt + ((size_t)(b * 8 + (seg - 16)) * 2048 + s) * 128;
            dst[lane]      = f2bf(o0);
            dst[lane + 64] = f2bf(o1);
        } else {
            unsigned short* dst = Vt + ((size_t)(b * 8 + (seg - 24)) * 2048 + s) * 128;
            dst[lane]      = row[col0 + lane];
            dst[lane + 64] = row[col0 + 64 + lane];
        }
    }
}

// ---------------- causal GQA flash attention ----------------
// 8 waves/block, QBLK=128, KVBLK=64; swapped QK^T lane-local softmax;
// heavy-first equal-qb dispatch order; defer-max (T13).
__global__ __launch_bounds__(512, 4) void k_attn(const unsigned short* __restrict__ Qt,
                                                 const unsigned short* __restrict__ Kt,
                                                 const unsigned short* __restrict__ Vtg,
                                                 unsigned short* __restrict__ attn) {
    __shared__ unsigned short Ks[64][136];     // K tile [kv][d], padded
    __shared__ unsigned short Vs[128][72];     // V^T tile [d][kv], padded
    __shared__ unsigned short Ps[8][16][72];   // per-wave P tile [q][kv], padded
    // heavy-first ordering: 32 consecutive bids share one qb (descending),
    // so co-resident blocks have equal/near-equal causal work under any
    // adjacent or strided block->CU assignment.
    int bid = blockIdx.x;                  // 0..511
    int qb = 15 - (bid >> 5);
    int bh = bid & 31;
    int b = bh >> 4, h = bh & 15;
    int kvh = h >> 1;
    int tid = threadIdx.x;
    int lane = tid & 63, wave = tid >> 6;
    int lr = lane & 15, lg = lane >> 4;
    int q0 = qb * 128;
    const unsigned short* Qb1 = Qt + ((size_t)bh * 2048 + q0 + wave * 16) * 128;
    const unsigned short* Kbase = Kt + (size_t)(b * 8 + kvh) * 2048 * 128;
    const unsigned short* Vtb   = Vtg + (size_t)(b * 8 + kvh) * 128 * 2048;   // [d][s]
    s16x8 aq[4];
    #pragma unroll
    for (int f = 0; f < 4; f++)
        aq[f] = *(const s16x8*)(Qb1 + (size_t)lr * 128 + f * 32 + lg * 8);
    f32x4 out[8] = {};
    float m_q = -1e30f, l_q = 0.f;
    int qglob = q0 + wave * 16 + lr;
    int qhi   = q0 + wave * 16 + 15;       // wave-uniform activity bound
    const float scale = 0.08838834764831845f;  // 1/sqrt(128)
    int ntiles = 2 * qb + 2;
    // staging coords (512 threads)
    int krow = tid >> 4, kcol = (tid & 15) * 8;   // K: 32 rows x 128 cols per pass, 2 passes
    int vrow = tid >> 3, vcol = (tid & 7) * 8;    // V^T: 64 rows x 64 cols per pass, 2 passes
    s16x8 kpre[2], vpre[2];
    #pragma unroll
    for (int p = 0; p < 2; p++) {
        kpre[p] = *(const s16x8*)(Kbase + (size_t)(krow + p * 32) * 128 + kcol);
        vpre[p] = *(const s16x8*)(Vtb + (size_t)(vrow + p * 64) * 2048 + vcol);
    }

    for (int t = 0; t < ntiles; t++) {
        int k0 = t * 64;
        __syncthreads();   // previous tile's LDS reads complete
        #pragma unroll
        for (int p = 0; p < 2; p++) {
            *(s16x8*)&Ks[krow + p * 32][kcol] = kpre[p];
            *(s16x8*)&Vs[vrow + p * 64][vcol] = vpre[p];
        }
        __syncthreads();
        if (t + 1 < ntiles) {
            int kn = k0 + 64;
            #pragma unroll
            for (int p = 0; p < 2; p++) {
                kpre[p] = *(const s16x8*)(Kbase + (size_t)(kn + krow + p * 32) * 128 + kcol);
                vpre[p] = *(const s16x8*)(Vtb + (size_t)(vrow + p * 64) * 2048 + kn + vcol);
            }
        }
        if (k0 <= qhi) {
            // swapped QK^T: S^T[kv][q], A-frag = K rows, B-frag = Q
            f32x4 st[4] = {};
            __builtin_amdgcn_s_setprio(1);
            #pragma unroll
            for (int sub = 0; sub < 4; sub++)
                #pragma unroll
                for (int f = 0; f < 4; f++) {
                    s16x8 bk = *(const s16x8*)&Ks[sub * 16 + lr][f * 32 + lg * 8];
                    st[sub] = __builtin_amdgcn_mfma_f32_16x16x32_bf16(bk, aq[f], st[sub], 0, 0, 0);
                }
            __builtin_amdgcn_s_setprio(0);
            // softmax in place: lane holds 16 values of row q=qglob
            float mx = -1e30f;
            #pragma unroll
            for (int sub = 0; sub < 4; sub++)
                #pragma unroll
                for (int r = 0; r < 4; r++) {
                    int kv = k0 + sub * 16 + lg * 4 + r;
                    float v = (kv <= qglob) ? st[sub][r] * scale : -1e30f;
                    st[sub][r] = v;
                    mx = fmaxf(mx, v);
                }
            mx = fmaxf(mx, __shfl_xor(mx, 16, 64));
            mx = fmaxf(mx, __shfl_xor(mx, 32, 64));
            // T13 defer-max: skip max-update + rescale when growth bounded
            bool defer = __all(mx <= m_q + 8.0f);
            float sf = 1.0f;
            if (!defer) {
                float mnew = fmaxf(m_q, mx);
                sf = __expf(m_q - mnew);
                m_q = mnew;
            }
            float rs = 0.f;
            #pragma unroll
            for (int sub = 0; sub < 4; sub++)
                #pragma unroll
                for (int r = 0; r < 4; r++) {
                    float e = __expf(st[sub][r] - m_q);
                    st[sub][r] = e;
                    rs += e;
                }
            rs += __shfl_xor(rs, 16, 64);
            rs += __shfl_xor(rs, 32, 64);
            l_q = defer ? (l_q + rs) : (l_q * sf + rs);
            // pack P -> Ps[q][kv], vectorized b64 writes
            #pragma unroll
            for (int sub = 0; sub < 4; sub++) {
                unsigned lop  = (unsigned)f2bf(st[sub][0]) | ((unsigned)f2bf(st[sub][1]) << 16);
                unsigned hip_ = (unsigned)f2bf(st[sub][2]) | ((unsigned)f2bf(st[sub][3]) << 16);
                uint2 w; w.x = lop; w.y = hip_;
                *(uint2*)&Ps[wave][lr][sub * 16 + lg * 4] = w;
            }
            if (!defer) {
                // rescale accumulator (per out row q = lg*4 + r)
                float sfr[4];
                #pragma unroll
                for (int r = 0; r < 4; r++) sfr[r] = __shfl(sf, lg * 4 + r, 64);
                #pragma unroll
                for (int blk = 0; blk < 8; blk++)
                    #pragma unroll
                    for (int r = 0; r < 4; r++) out[blk][r] *= sfr[r];
            }
            // PV: P (16x64) x V^T tile
            __builtin_amdgcn_s_setprio(1);
            #pragma unroll
            for (int ks = 0; ks < 2; ks++) {
                s16x8 ap = *(const s16x8*)&Ps[wave][lr][ks * 32 + lg * 8];
                #pragma unroll
                for (int blk = 0; blk < 8; blk++) {
                    s16x8 bv = *(const s16x8*)&Vs[blk * 16 + lr][ks * 32 + lg * 8];
                    out[blk] = __builtin_amdgcn_mfma_f32_16x16x32_bf16(ap, bv, out[blk], 0, 0, 0);
                }
            }
            __builtin_amdgcn_s_setprio(0);
        }
    }
    float linv = 1.0f / l_q;
    float inv[4];
    #pragma unroll
    for (int r = 0; r < 4; r++) inv[r] = __shfl(linv, lg * 4 + r, 64);
    #pragma unroll
    for (int blk = 0; blk < 8; blk++)
        #pragma unroll
        for (int r = 0; r < 4; r++) {
            int row = q0 + wave * 16 + lg * 4 + r;
            attn[((size_t)(b * 2048) + row) * 2048 + h * 128 + blk * 16 + lr] =
                f2bf(out[blk][r] * inv[r]);
        }
}

extern "C" void kernel_launch(void* const* d_in, const int* in_sizes, int n_in,
                              void* d_out, int out_size, void* d_ws, size_t ws_size,
                              hipStream_t stream) {
    const float* x    = (const float*)d_in[0];
    const float* wq   = (const float*)d_in[1];
    const float* wk   = (const float*)d_in[2];
    const float* wv   = (const float*)d_in[3];
    const float* wo   = (const float*)d_in[4];
    const float* qg   = (const float*)d_in[5];
    const float* kg   = (const float*)d_in[6];
    const float* cosc = (const float*)d_in[7];
    const float* sinc = (const float*)d_in[8];

    char* ws = (char*)d_ws;
    unsigned short* xb   = (unsigned short*)(ws);                 // 16 MiB  x bf16 (4096x2048)
    unsigned short* w1t  = (unsigned short*)(ws + 16777216);      // 16 MiB  [wq|wk|wv]^T (4096x2048)
    unsigned short* w2t  = (unsigned short*)(ws + 33554432);      //  8 MiB  wo^T (2048x2048)
    unsigned short* qkv  = (unsigned short*)(ws + 41943040);      // 32 MiB  (4096x4096); dead after k_rms_rope
    unsigned short* Qt   = (unsigned short*)(ws + 75497472);      // 16 MiB  (2,16,2048,128)
    unsigned short* Kt   = (unsigned short*)(ws + 92274688);      //  8 MiB  (2,8,2048,128)
    unsigned short* Vt   = (unsigned short*)(ws + 100663296);     //  8 MiB  (2,8,2048,128)
    unsigned short* attn = (unsigned short*)(ws + 109051904);     // 16 MiB  (4096x2048)
    unsigned short* Vtg  = qkv;                                   //  8 MiB  (2,8,128,2048) reuses qkv

    k_convert_x<<<4096, 256, 0, stream>>>(x, xb, 8388608);
    k_transpose_w<<<dim3(64, 64), 256, 0, stream>>>(wq, w1t, 2048, 2048, 0, 2048);
    k_transpose_w<<<dim3(64, 32), 256, 0, stream>>>(wk, w1t, 2048, 1024, 2048, 2048);
    k_transpose_w<<<dim3(64, 32), 256, 0, stream>>>(wv, w1t, 2048, 1024, 3072, 2048);
    k_transpose_w<<<dim3(64, 64), 256, 0, stream>>>(wo, w2t, 2048, 2048, 0, 2048);
    k_gemm256<0><<<dim3(16, 16), 512, 0, stream>>>(xb, w1t, qkv, 4096, 4096, 2048);
    k_rms_rope<<<4096, 256, 0, stream>>>(qkv, qg, kg, cosc, sinc, Qt, Kt, Vt);
    k_transpose_v<<<dim3(64, 4, 16), 256, 0, stream>>>(Vt, Vtg);
    k_attn<<<512, 512, 0, stream>>>(Qt, Kt, Vtg, attn);
    k_gemm_bt<1><<<dim3(32, 16), 256, 0, stream>>>(attn, w2t, d_out, 4096, 2048, 2048);
}

// Round 8
// 239.228 us; speedup vs baseline: 1.0820x; 1.0820x over previous
//
#include <hip/hip_runtime.h>
#include <hip/hip_bf16.h>

// Problem constants: B=2, S=2048, DIM=2048, H=16, KVH=8, D=128

typedef __attribute__((ext_vector_type(8))) short s16x8;   // 8 bf16 in 4 VGPRs
typedef __attribute__((ext_vector_type(4))) float f32x4;

typedef const __attribute__((address_space(1))) void* gas_t;
typedef __attribute__((address_space(3))) void* las_t;
#define GLL16(g, l) __builtin_amdgcn_global_load_lds((gas_t)(const void*)(g), (las_t)(void*)(l), 16, 0, 0)

static __device__ __forceinline__ unsigned short f2bf(float f) {
    union { float f; unsigned u; } v; v.f = f;
    unsigned r = v.u + 0x7FFF + ((v.u >> 16) & 1);   // RNE
    return (unsigned short)(r >> 16);
}
static __device__ __forceinline__ float bf2f(unsigned short h) {
    union { unsigned u; float f; } v; v.u = ((unsigned)h) << 16;
    return v.f;
}
static __device__ __forceinline__ float exp2_fast(float x) {
    float r; asm("v_exp_f32 %0, %1" : "=v"(r) : "v"(x)); return r;
}

// scale(1/sqrt(128)) * log2(e): baked into Q so softmax runs in exp2 domain
#define SCALE_L2E 0.12751744900929f

// ---------------- f32 -> bf16 elementwise convert (x) ----------------
__global__ __launch_bounds__(256) void k_convert_x(const float* __restrict__ x,
                                                   unsigned short* __restrict__ xb, int n) {
    int i = (blockIdx.x * 256 + threadIdx.x) * 8;
    if (i >= n) return;
    float4 a = *(const float4*)(x + i);
    float4 b = *(const float4*)(x + i + 4);
    s16x8 o;
    o[0] = (short)f2bf(a.x); o[1] = (short)f2bf(a.y); o[2] = (short)f2bf(a.z); o[3] = (short)f2bf(a.w);
    o[4] = (short)f2bf(b.x); o[5] = (short)f2bf(b.y); o[6] = (short)f2bf(b.z); o[7] = (short)f2bf(b.w);
    *(s16x8*)(xb + i) = o;
}

// ---------------- weight transpose f32 (K x N) -> bf16 (N x K) ----------------
__global__ __launch_bounds__(256) void k_transpose_w(const float* __restrict__ src,
                                                     unsigned short* __restrict__ dst,
                                                     int K, int N, int nbase, int dstld) {
    __shared__ float t[32][33];
    int k0 = blockIdx.x * 32, n0 = blockIdx.y * 32;
    int tx = threadIdx.x & 31, ty0 = threadIdx.x >> 5;
    for (int p = 0; p < 4; p++) {
        int ty = ty0 + p * 8;
        t[ty][tx] = src[(size_t)(k0 + ty) * N + n0 + tx];
    }
    __syncthreads();
    for (int p = 0; p < 4; p++) {
        int ty = ty0 + p * 8;
        dst[(size_t)(nbase + n0 + ty) * dstld + k0 + tx] = f2bf(t[tx][ty]);
    }
}

// ---------------- bf16 transpose: V (2048 x 128) -> Vt (128 x 2048), per (b,kvh) ----------------
__global__ __launch_bounds__(256) void k_transpose_v(const unsigned short* __restrict__ V,
                                                     unsigned short* __restrict__ Vt) {
    __shared__ unsigned short t[32][33];
    int s0 = blockIdx.x * 32, d0 = blockIdx.y * 32;
    size_t base = (size_t)blockIdx.z * 2048 * 128;
    int tx = threadIdx.x & 31, ty0 = threadIdx.x >> 5;
    for (int p = 0; p < 4; p++) {
        int ty = ty0 + p * 8;
        t[ty][tx] = V[base + (size_t)(s0 + ty) * 128 + d0 + tx];
    }
    __syncthreads();
    for (int p = 0; p < 4; p++) {
        int ty = ty0 + p * 8;
        Vt[base + (size_t)(d0 + ty) * 2048 + s0 + tx] = t[tx][ty];
    }
}

// ---------------- 8-phase 256x256 GEMM: C = A(MxK) * Bt(NxK)^T ----------------
template<int OUTF32>
__global__ __launch_bounds__(512, 2) void k_gemm256(const unsigned short* __restrict__ A,
                                                    const unsigned short* __restrict__ Bt,
                                                    void* __restrict__ Cout,
                                                    int M, int N, int K) {
    __shared__ unsigned short As[2][256 * 64];
    __shared__ unsigned short Bs[2][256 * 64];
    int tid = threadIdx.x, lane = tid & 63, wave = tid >> 6;
    int wm = wave >> 2, wn = wave & 3;
    int lr = lane & 15, lg = lane >> 4;
    int srow = wave * 8 + (lane >> 3);
    int scol = (((lane & 7) ^ (lane >> 3)) * 8);
    const unsigned short* Ag = A  + (size_t)(blockIdx.x * 256 + srow) * K + scol;
    const unsigned short* Bg = Bt + (size_t)(blockIdx.y * 256 + srow) * K + scol;
    int ldsoff = wave * 512;

    f32x4 acc[8][4] = {};
    int NK = K / 64;
    #pragma unroll
    for (int p = 0; p < 4; p++) {
        GLL16(Ag + (size_t)p * 64 * K, &As[0][p * 4096 + ldsoff]);
        GLL16(Bg + (size_t)p * 64 * K, &Bs[0][p * 4096 + ldsoff]);
    }
    for (int t = 0; t < NK; ++t) {
        int slot = t & 1, nslot = slot ^ 1;
        size_t kn = (size_t)(t + 1) * 64;
        bool more = (t + 1) < NK;
        if (more) {
            GLL16(Ag + kn, &As[nslot][ldsoff]);
            GLL16(Bg + kn, &Bs[nslot][ldsoff]);
            asm volatile("s_waitcnt vmcnt(2)" ::: "memory");
        } else {
            asm volatile("s_waitcnt vmcnt(0)" ::: "memory");
        }
        __builtin_amdgcn_s_barrier();
        asm volatile("" ::: "memory");
        s16x8 bf[4][2];
        #pragma unroll
        for (int n = 0; n < 4; n++)
            #pragma unroll
            for (int kk = 0; kk < 2; kk++)
                bf[n][kk] = *(const s16x8*)&Bs[slot][(wn * 64 + n * 16 + lr) * 64 +
                                                     ((kk * 32 + lg * 8) ^ ((lr & 7) << 3))];
        #pragma unroll
        for (int q = 0; q < 4; q++) {
            s16x8 af[2][2];
            #pragma unroll
            for (int mm = 0; mm < 2; mm++)
                #pragma unroll
                for (int kk = 0; kk < 2; kk++)
                    af[mm][kk] = *(const s16x8*)&As[slot][(wm * 128 + (q * 2 + mm) * 16 + lr) * 64 +
                                                          ((kk * 32 + lg * 8) ^ ((lr & 7) << 3))];
            if (more && q < 3) {
                GLL16(Ag + (size_t)(q + 1) * 64 * K + kn, &As[nslot][(q + 1) * 4096 + ldsoff]);
                GLL16(Bg + (size_t)(q + 1) * 64 * K + kn, &Bs[nslot][(q + 1) * 4096 + ldsoff]);
            }
            __builtin_amdgcn_s_barrier();
            __builtin_amdgcn_s_setprio(1);
            #pragma unroll
            for (int mm = 0; mm < 2; mm++)
                #pragma unroll
                for (int n = 0; n < 4; n++)
                    #pragma unroll
                    for (int kk = 0; kk < 2; kk++)
                        acc[q * 2 + mm][n] = __builtin_amdgcn_mfma_f32_16x16x32_bf16(
                            af[mm][kk], bf[n][kk], acc[q * 2 + mm][n], 0, 0, 0);
            __builtin_amdgcn_s_setprio(0);
            __builtin_amdgcn_s_barrier();
        }
    }
    int rbase = blockIdx.x * 256 + wm * 128;
    int cbase = blockIdx.y * 256 + wn * 64;
    #pragma unroll
    for (int am = 0; am < 8; am++)
        #pragma unroll
        for (int n = 0; n < 4; n++)
            #pragma unroll
            for (int r = 0; r < 4; r++) {
                int row = rbase + am * 16 + lg * 4 + r;
                int col = cbase + n * 16 + lr;
                float v = acc[am][n][r];
                if (OUTF32) ((float*)Cout)[(size_t)row * N + col] = v;
                else        ((unsigned short*)Cout)[(size_t)row * N + col] = f2bf(v);
            }
}

// ---------------- GEMM: 128x128 m97 structure (kept for gemm2, N=2048) ----------------
template<int OUTF32>
__global__ __launch_bounds__(256) void k_gemm_bt(const unsigned short* __restrict__ A,
                                                 const unsigned short* __restrict__ Bt,
                                                 void* __restrict__ Cout,
                                                 int M, int N, int K) {
    __shared__ unsigned short As[128 * 32];
    __shared__ unsigned short Bs[128 * 32];
    int tid = threadIdx.x;
    int lane = tid & 63;
    int wave = tid >> 6;
    int wm = wave >> 1, wn = wave & 1;
    int lr = lane & 15, lk = (lane >> 4) * 8;
    int srow = wave * 32 + (lane >> 2);
    int scol = (lane & 3) * 8;
    const unsigned short* Ag0 = A  + (size_t)(blockIdx.x * 128 + srow) * K + scol;
    const unsigned short* Ag1 = Ag0 + (size_t)16 * K;
    const unsigned short* Bg0 = Bt + (size_t)(blockIdx.y * 128 + srow) * K + scol;
    const unsigned short* Bg1 = Bg0 + (size_t)16 * K;
    unsigned short* Asw = &As[wave * 1024];
    unsigned short* Bsw = &Bs[wave * 1024];
    f32x4 acc[4][4] = {};
    for (int k0 = 0; k0 < K; k0 += 32) {
        __syncthreads();
        GLL16(Ag0 + k0, Asw);
        GLL16(Ag1 + k0, Asw + 512);
        GLL16(Bg0 + k0, Bsw);
        GLL16(Bg1 + k0, Bsw + 512);
        __syncthreads();
        s16x8 af[4], bfr[4];
        #pragma unroll
        for (int m = 0; m < 4; m++) af[m]  = *(const s16x8*)&As[(wm * 64 + m * 16 + lr) * 32 + lk];
        #pragma unroll
        for (int n = 0; n < 4; n++) bfr[n] = *(const s16x8*)&Bs[(wn * 64 + n * 16 + lr) * 32 + lk];
        #pragma unroll
        for (int m = 0; m < 4; m++)
            #pragma unroll
            for (int n = 0; n < 4; n++)
                acc[m][n] = __builtin_amdgcn_mfma_f32_16x16x32_bf16(af[m], bfr[n], acc[m][n], 0, 0, 0);
    }
    int rbase = blockIdx.x * 128 + wm * 64;
    int cbase = blockIdx.y * 128 + wn * 64;
    #pragma unroll
    for (int m = 0; m < 4; m++)
        #pragma unroll
        for (int n = 0; n < 4; n++)
            #pragma unroll
            for (int r = 0; r < 4; r++) {
                int row = rbase + m * 16 + (lane >> 4) * 4 + r;
                int col = cbase + n * 16 + lr;
                float v = acc[m][n][r];
                if (OUTF32) ((float*)Cout)[(size_t)row * N + col] = v;
                else        ((unsigned short*)Cout)[(size_t)row * N + col] = f2bf(v);
            }
}

// ---------------- fused RMSNorm + RoPE + head transpose (vectorized) ----------------
// one block per (b,s) row; 2 passes; wave covers 4 contiguous 128-wide segments;
// lane li=lane&15 owns 8 contiguous d; RoPE partner via shfl_xor(8).
// Q output pre-scaled by SCALE_L2E (softmax runs in exp2 domain).
__global__ __launch_bounds__(256) void k_rms_rope(const unsigned short* __restrict__ qkv,
                                                  const float* __restrict__ qg,
                                                  const float* __restrict__ kg,
                                                  const float* __restrict__ cosc,
                                                  const float* __restrict__ sinc,
                                                  unsigned short* __restrict__ Qt,
                                                  unsigned short* __restrict__ Kt,
                                                  unsigned short* __restrict__ Vt) {
    int r = blockIdx.x;            // b*2048 + s
    int b = r >> 11;
    int s = r & 2047;
    int tid = threadIdx.x;
    int wave = tid >> 6, lane = tid & 63;
    int sl = lane >> 4;            // local segment 0..3
    int li = lane & 15;
    int d0 = li * 8;               // 0..120
    const unsigned short* row = qkv + (size_t)r * 4096;
    #pragma unroll
    for (int p = 0; p < 2; p++) {
        int seg = p * 16 + wave * 4 + sl;   // 0..31, wave-uniform type
        s16x8 raw = *(const s16x8*)(row + seg * 128 + d0);
        if (seg >= 24) {   // V: straight copy (wave-uniform branch)
            *(s16x8*)(Vt + ((size_t)(b * 8 + (seg - 24)) * 2048 + s) * 128 + d0) = raw;
            continue;
        }
        float e[8];
        #pragma unroll
        for (int j = 0; j < 8; j++) e[j] = bf2f((unsigned short)raw[j]);
        float ssq = 0.f;
        #pragma unroll
        for (int j = 0; j < 8; j++) ssq += e[j] * e[j];
        ssq += __shfl_xor(ssq, 1, 64);
        ssq += __shfl_xor(ssq, 2, 64);
        ssq += __shfl_xor(ssq, 4, 64);
        ssq += __shfl_xor(ssq, 8, 64);
        float rn = rsqrtf(ssq * (1.0f / 128.0f) + 1e-6f);
        const float* g = (seg < 16) ? qg : kg;
        float gs = (seg < 16) ? SCALE_L2E : 1.0f;
        float4 g0 = *(const float4*)(g + d0);
        float4 g1 = *(const float4*)(g + d0 + 4);
        float t[8];
        t[0] = e[0] * rn * g0.x * gs; t[1] = e[1] * rn * g0.y * gs;
        t[2] = e[2] * rn * g0.z * gs; t[3] = e[3] * rn * g0.w * gs;
        t[4] = e[4] * rn * g1.x * gs; t[5] = e[5] * rn * g1.y * gs;
        t[6] = e[6] * rn * g1.z * gs; t[7] = e[7] * rn * g1.w * gs;
        float pr[8];
        #pragma unroll
        for (int j = 0; j < 8; j++) pr[j] = __shfl_xor(t[j], 8, 64);
        int didx = d0 & 63;
        float4 c0 = *(const float4*)(cosc + (size_t)s * 64 + didx);
        float4 c1 = *(const float4*)(cosc + (size_t)s * 64 + didx + 4);
        float4 sn0 = *(const float4*)(sinc + (size_t)s * 64 + didx);
        float4 sn1 = *(const float4*)(sinc + (size_t)s * 64 + didx + 4);
        float cv[8] = {c0.x, c0.y, c0.z, c0.w, c1.x, c1.y, c1.z, c1.w};
        float sv[8] = {sn0.x, sn0.y, sn0.z, sn0.w, sn1.x, sn1.y, sn1.z, sn1.w};
        float sgn = (li < 8) ? -1.0f : 1.0f;
        s16x8 o;
        #pragma unroll
        for (int j = 0; j < 8; j++)
            o[j] = (short)f2bf(t[j] * cv[j] + sgn * pr[j] * sv[j]);
        unsigned short* dst = (seg < 16)
            ? Qt + ((size_t)(b * 16 + seg) * 2048 + s) * 128 + d0
            : Kt + ((size_t)(b * 8 + (seg - 16)) * 2048 + s) * 128 + d0;
        *(s16x8*)dst = o;
    }
}

// ---------------- causal GQA flash attention ----------------
// 8 waves/block, QBLK=128, KVBLK=64; swapped QK^T lane-local softmax in exp2
// domain (scale baked into Q); complementary-qb balanced swizzle (R5);
// defer-max (T13); interior tiles skip causal masking.
__global__ __launch_bounds__(512, 4) void k_attn(const unsigned short* __restrict__ Qt,
                                                 const unsigned short* __restrict__ Kt,
                                                 const unsigned short* __restrict__ Vtg,
                                                 unsigned short* __restrict__ attn) {
    __shared__ unsigned short Ks[64][136];     // K tile [kv][d], padded
    __shared__ unsigned short Vs[128][72];     // V^T tile [d][kv], padded
    __shared__ unsigned short Ps[8][16][72];   // per-wave P tile [q][kv], padded
    // duration-balanced swizzle (R5): blocks bid and bid+256 have complementary qb
    int bid = blockIdx.x;                  // 0..511
    int lo = bid & 255;
    int qb, bh;
    if (bid < 256) { qb = lo & 15;        bh = lo >> 4; }
    else           { qb = 15 - (lo & 15); bh = 16 + (lo >> 4); }
    int b = bh >> 4, h = bh & 15;
    int kvh = h >> 1;
    int tid = threadIdx.x;
    int lane = tid & 63, wave = tid >> 6;
    int lr = lane & 15, lg = lane >> 4;
    int q0 = qb * 128;
    const unsigned short* Qb1 = Qt + ((size_t)bh * 2048 + q0 + wave * 16) * 128;
    const unsigned short* Kbase = Kt + (size_t)(b * 8 + kvh) * 2048 * 128;
    const unsigned short* Vtb   = Vtg + (size_t)(b * 8 + kvh) * 128 * 2048;   // [d][s]
    s16x8 aq[4];
    #pragma unroll
    for (int f = 0; f < 4; f++)
        aq[f] = *(const s16x8*)(Qb1 + (size_t)lr * 128 + f * 32 + lg * 8);
    f32x4 out[8] = {};
    float m_q = -1e30f, l_q = 0.f;
    int qglob = q0 + wave * 16 + lr;
    int qlo   = q0 + wave * 16;            // wave-uniform bounds
    int qhi   = qlo + 15;
    int ntiles = 2 * qb + 2;
    // staging coords (512 threads)
    int krow = tid >> 4, kcol = (tid & 15) * 8;   // K: 32 rows x 128 cols per pass, 2 passes
    int vrow = tid >> 3, vcol = (tid & 7) * 8;    // V^T: 64 rows x 64 cols per pass, 2 passes
    s16x8 kpre[2], vpre[2];
    #pragma unroll
    for (int p = 0; p < 2; p++) {
        kpre[p] = *(const s16x8*)(Kbase + (size_t)(krow + p * 32) * 128 + kcol);
        vpre[p] = *(const s16x8*)(Vtb + (size_t)(vrow + p * 64) * 2048 + vcol);
    }

    for (int t = 0; t < ntiles; t++) {
        int k0 = t * 64;
        __syncthreads();   // previous tile's LDS reads complete
        #pragma unroll
        for (int p = 0; p < 2; p++) {
            *(s16x8*)&Ks[krow + p * 32][kcol] = kpre[p];
            *(s16x8*)&Vs[vrow + p * 64][vcol] = vpre[p];
        }
        __syncthreads();
        if (t + 1 < ntiles) {
            int kn = k0 + 64;
            #pragma unroll
            for (int p = 0; p < 2; p++) {
                kpre[p] = *(const s16x8*)(Kbase + (size_t)(kn + krow + p * 32) * 128 + kcol);
                vpre[p] = *(const s16x8*)(Vtb + (size_t)(vrow + p * 64) * 2048 + kn + vcol);
            }
        }
        if (k0 <= qhi) {
            // swapped QK^T: S^T[kv][q] in exp2 domain (scale*log2e baked into Q)
            f32x4 st[4] = {};
            __builtin_amdgcn_s_setprio(1);
            #pragma unroll
            for (int sub = 0; sub < 4; sub++)
                #pragma unroll
                for (int f = 0; f < 4; f++) {
                    s16x8 bk = *(const s16x8*)&Ks[sub * 16 + lr][f * 32 + lg * 8];
                    st[sub] = __builtin_amdgcn_mfma_f32_16x16x32_bf16(bk, aq[f], st[sub], 0, 0, 0);
                }
            __builtin_amdgcn_s_setprio(0);
            // causal mask only on boundary tiles (wave-uniform test)
            float mx = -1e30f;
            if (k0 + 63 > qlo) {
                #pragma unroll
                for (int sub = 0; sub < 4; sub++)
                    #pragma unroll
                    for (int r = 0; r < 4; r++) {
                        int kv = k0 + sub * 16 + lg * 4 + r;
                        if (kv > qglob) st[sub][r] = -1e30f;
                        mx = fmaxf(mx, st[sub][r]);
                    }
            } else {
                #pragma unroll
                for (int sub = 0; sub < 4; sub++)
                    #pragma unroll
                    for (int r = 0; r < 4; r++) mx = fmaxf(mx, st[sub][r]);
            }
            mx = fmaxf(mx, __shfl_xor(mx, 16, 64));
            mx = fmaxf(mx, __shfl_xor(mx, 32, 64));
            // T13 defer-max: skip max-update + rescale when growth bounded (2^8)
            bool defer = __all(mx <= m_q + 8.0f);
            float sf = 1.0f;
            if (!defer) {
                float mnew = fmaxf(m_q, mx);
                sf = exp2_fast(m_q - mnew);
                m_q = mnew;
            }
            float rs = 0.f;
            #pragma unroll
            for (int sub = 0; sub < 4; sub++)
                #pragma unroll
                for (int r = 0; r < 4; r++) {
                    float e = exp2_fast(st[sub][r] - m_q);
                    st[sub][r] = e;
                    rs += e;
                }
            rs += __shfl_xor(rs, 16, 64);
            rs += __shfl_xor(rs, 32, 64);
            l_q = defer ? (l_q + rs) : (l_q * sf + rs);
            // pack P -> Ps[q][kv], vectorized b64 writes
            #pragma unroll
            for (int sub = 0; sub < 4; sub++) {
                unsigned lop  = (unsigned)f2bf(st[sub][0]) | ((unsigned)f2bf(st[sub][1]) << 16);
                unsigned hip_ = (unsigned)f2bf(st[sub][2]) | ((unsigned)f2bf(st[sub][3]) << 16);
                uint2 w; w.x = lop; w.y = hip_;
                *(uint2*)&Ps[wave][lr][sub * 16 + lg * 4] = w;
            }
            if (!defer) {
                float sfr[4];
                #pragma unroll
                for (int r = 0; r < 4; r++) sfr[r] = __shfl(sf, lg * 4 + r, 64);
                #pragma unroll
                for (int blk = 0; blk < 8; blk++)
                    #pragma unroll
                    for (int r = 0; r < 4; r++) out[blk][r] *= sfr[r];
            }
            // PV: P (16x64) x V^T tile
            __builtin_amdgcn_s_setprio(1);
            #pragma unroll
            for (int ks = 0; ks < 2; ks++) {
                s16x8 ap = *(const s16x8*)&Ps[wave][lr][ks * 32 + lg * 8];
                #pragma unroll
                for (int blk = 0; blk < 8; blk++) {
                    s16x8 bv = *(const s16x8*)&Vs[blk * 16 + lr][ks * 32 + lg * 8];
                    out[blk] = __builtin_amdgcn_mfma_f32_16x16x32_bf16(ap, bv, out[blk], 0, 0, 0);
                }
            }
            __builtin_amdgcn_s_setprio(0);
        }
    }
    float linv = 1.0f / l_q;
    float inv[4];
    #pragma unroll
    for (int r = 0; r < 4; r++) inv[r] = __shfl(linv, lg * 4 + r, 64);
    #pragma unroll
    for (int blk = 0; blk < 8; blk++)
        #pragma unroll
        for (int r = 0; r < 4; r++) {
            int row = q0 + wave * 16 + lg * 4 + r;
            attn[((size_t)(b * 2048) + row) * 2048 + h * 128 + blk * 16 + lr] =
                f2bf(out[blk][r] * inv[r]);
        }
}

extern "C" void kernel_launch(void* const* d_in, const int* in_sizes, int n_in,
                              void* d_out, int out_size, void* d_ws, size_t ws_size,
                              hipStream_t stream) {
    const float* x    = (const float*)d_in[0];
    const float* wq   = (const float*)d_in[1];
    const float* wk   = (const float*)d_in[2];
    const float* wv   = (const float*)d_in[3];
    const float* wo   = (const float*)d_in[4];
    const float* qg   = (const float*)d_in[5];
    const float* kg   = (const float*)d_in[6];
    const float* cosc = (const float*)d_in[7];
    const float* sinc = (const float*)d_in[8];

    char* ws = (char*)d_ws;
    unsigned short* xb   = (unsigned short*)(ws);                 // 16 MiB  x bf16 (4096x2048)
    unsigned short* w1t  = (unsigned short*)(ws + 16777216);      // 16 MiB  [wq|wk|wv]^T (4096x2048)
    unsigned short* w2t  = (unsigned short*)(ws + 33554432);      //  8 MiB  wo^T (2048x2048)
    unsigned short* qkv  = (unsigned short*)(ws + 41943040);      // 32 MiB  (4096x4096); dead after k_rms_rope
    unsigned short* Qt   = (unsigned short*)(ws + 75497472);      // 16 MiB  (2,16,2048,128)
    unsigned short* Kt   = (unsigned short*)(ws + 92274688);      //  8 MiB  (2,8,2048,128)
    unsigned short* Vt   = (unsigned short*)(ws + 100663296);     //  8 MiB  (2,8,2048,128)
    unsigned short* attn = (unsigned short*)(ws + 109051904);     // 16 MiB  (4096x2048)
    unsigned short* Vtg  = qkv;                                   //  8 MiB  (2,8,128,2048) reuses qkv

    k_convert_x<<<4096, 256, 0, stream>>>(x, xb, 8388608);
    k_transpose_w<<<dim3(64, 64), 256, 0, stream>>>(wq, w1t, 2048, 2048, 0, 2048);
    k_transpose_w<<<dim3(64, 32), 256, 0, stream>>>(wk, w1t, 2048, 1024, 2048, 2048);
    k_transpose_w<<<dim3(64, 32), 256, 0, stream>>>(wv, w1t, 2048, 1024, 3072, 2048);
    k_transpose_w<<<dim3(64, 64), 256, 0, stream>>>(wo, w2t, 2048, 2048, 0, 2048);
    k_gemm256<0><<<dim3(16, 16), 512, 0, stream>>>(xb, w1t, qkv, 4096, 4096, 2048);
    k_rms_rope<<<4096, 256, 0, stream>>>(qkv, qg, kg, cosc, sinc, Qt, Kt, Vt);
    k_transpose_v<<<dim3(64, 4, 16), 256, 0, stream>>>(Vt, Vtg);
    k_attn<<<512, 512, 0, stream>>>(Qt, Kt, Vtg, attn);
    k_gemm_bt<1><<<dim3(32, 16), 256, 0, stream>>>(attn, w2t, d_out, 4096, 2048, 2048);
}

// Round 9
// 236.622 us; speedup vs baseline: 1.0939x; 1.0110x over previous
//
#include <hip/hip_runtime.h>
#include <hip/hip_bf16.h>

// Problem constants: B=2, S=2048, DIM=2048, H=16, KVH=8, D=128

typedef __attribute__((ext_vector_type(8))) short s16x8;   // 8 bf16 in 4 VGPRs
typedef __attribute__((ext_vector_type(4))) float f32x4;

typedef const __attribute__((address_space(1))) void* gas_t;
typedef __attribute__((address_space(3))) void* las_t;
#define GLL16(g, l) __builtin_amdgcn_global_load_lds((gas_t)(const void*)(g), (las_t)(void*)(l), 16, 0, 0)

static __device__ __forceinline__ unsigned short f2bf(float f) {
    union { float f; unsigned u; } v; v.f = f;
    unsigned r = v.u + 0x7FFF + ((v.u >> 16) & 1);   // RNE
    return (unsigned short)(r >> 16);
}
static __device__ __forceinline__ float bf2f(unsigned short h) {
    union { unsigned u; float f; } v; v.u = ((unsigned)h) << 16;
    return v.f;
}
static __device__ __forceinline__ float exp2_fast(float x) {
    float r; asm("v_exp_f32 %0, %1" : "=v"(r) : "v"(x)); return r;
}

// scale(1/sqrt(128)) * log2(e): baked into Q so softmax runs in exp2 domain
#define SCALE_L2E 0.12751744900929f

// ---------------- f32 -> bf16 elementwise convert (x) ----------------
__global__ __launch_bounds__(256) void k_convert_x(const float* __restrict__ x,
                                                   unsigned short* __restrict__ xb, int n) {
    int i = (blockIdx.x * 256 + threadIdx.x) * 8;
    if (i >= n) return;
    float4 a = *(const float4*)(x + i);
    float4 b = *(const float4*)(x + i + 4);
    s16x8 o;
    o[0] = (short)f2bf(a.x); o[1] = (short)f2bf(a.y); o[2] = (short)f2bf(a.z); o[3] = (short)f2bf(a.w);
    o[4] = (short)f2bf(b.x); o[5] = (short)f2bf(b.y); o[6] = (short)f2bf(b.z); o[7] = (short)f2bf(b.w);
    *(s16x8*)(xb + i) = o;
}

// ---------------- weight transpose f32 (K x N) -> bf16 (N x K) ----------------
__global__ __launch_bounds__(256) void k_transpose_w(const float* __restrict__ src,
                                                     unsigned short* __restrict__ dst,
                                                     int K, int N, int nbase, int dstld) {
    __shared__ float t[32][33];
    int k0 = blockIdx.x * 32, n0 = blockIdx.y * 32;
    int tx = threadIdx.x & 31, ty0 = threadIdx.x >> 5;
    for (int p = 0; p < 4; p++) {
        int ty = ty0 + p * 8;
        t[ty][tx] = src[(size_t)(k0 + ty) * N + n0 + tx];
    }
    __syncthreads();
    for (int p = 0; p < 4; p++) {
        int ty = ty0 + p * 8;
        dst[(size_t)(nbase + n0 + ty) * dstld + k0 + tx] = f2bf(t[tx][ty]);
    }
}

// ---------------- bf16 transpose: V (2048 x 128) -> Vt (128 x 2048), per (b,kvh) ----------------
__global__ __launch_bounds__(256) void k_transpose_v(const unsigned short* __restrict__ V,
                                                     unsigned short* __restrict__ Vt) {
    __shared__ unsigned short t[32][33];
    int s0 = blockIdx.x * 32, d0 = blockIdx.y * 32;
    size_t base = (size_t)blockIdx.z * 2048 * 128;
    int tx = threadIdx.x & 31, ty0 = threadIdx.x >> 5;
    for (int p = 0; p < 4; p++) {
        int ty = ty0 + p * 8;
        t[ty][tx] = V[base + (size_t)(s0 + ty) * 128 + d0 + tx];
    }
    __syncthreads();
    for (int p = 0; p < 4; p++) {
        int ty = ty0 + p * 8;
        Vt[base + (size_t)(d0 + ty) * 2048 + s0 + tx] = t[tx][ty];
    }
}

// ---------------- 256x256 GEMM, K-split chunk pipeline with counted vmcnt ----------------
// 512 thr (8 waves 2Mx4N), BK=64 staged as 4 chunks {A.kk0, B.kk0, A.kk1, B.kk1}
// of 256x32 each; phase p depends on exactly one chunk pair -> vmcnt(6) keeps
// 3 chunks in flight (true T4). XOR-swizzled (write: pre-swizzled global src;
// read: same involution). 2 barriers/phase, setprio around MFMA.
template<int OUTF32>
__global__ __launch_bounds__(512, 2) void k_gemm256(const unsigned short* __restrict__ A,
                                                    const unsigned short* __restrict__ Bt,
                                                    void* __restrict__ Cout,
                                                    int M, int N, int K) {
    __shared__ unsigned short Ls[2][2][2][8192];   // [slot][mat A=0/B=1][kk][256*32] = 128 KiB
    int tid = threadIdx.x, lane = tid & 63, wave = tid >> 6;
    int wm = wave >> 2, wn = wave & 3;
    int lr = lane & 15, lg = lane >> 4;
    // staging: per chunk 2 GLL (one per 128-row half); wave covers rows wave*16..+15
    int swrow = wave * 16 + (lane >> 2);              // row within half (0..127)
    int ssw   = ((lane >> 2) & 3) ^ lg;               // write-side swizzle = sw(full row)
    int scol  = ((lane & 3) ^ ssw) * 8;               // pre-swizzled source col (elems)
    const unsigned short* Ab = A  + (size_t)(blockIdx.x * 256) * K;
    const unsigned short* Bb = Bt + (size_t)(blockIdx.y * 256) * K;
    int cgr = (lg ^ (lr & 3) ^ ((lr >> 2) & 3)) * 8;  // read-side swizzled col (elems)

    f32x4 acc[8][4] = {};
    int NK = K / 64;

    auto issue = [&](int slot, int mat, int kk, int k0) {
        const unsigned short* base = mat ? Bb : Ab;
        unsigned short* dst = &Ls[slot][mat][kk][wave * 512];
        GLL16(base + (size_t)swrow * K + k0 + kk * 32 + scol, dst);
        GLL16(base + (size_t)(swrow + 128) * K + k0 + kk * 32 + scol, dst + 4096);
    };

    // prologue: tile 0 fully staged into slot 0, chunk order C0,C1,C2,C3
    issue(0, 0, 0, 0);
    issue(0, 1, 0, 0);
    issue(0, 0, 1, 0);
    issue(0, 1, 1, 0);

    for (int t = 0; t < NK; ++t) {
        int slot = t & 1, nslot = slot ^ 1;
        int kn = (t + 1) * 64;
        bool more = (t + 1) < NK;
        const unsigned short* As0 = Ls[slot][0][0];
        const unsigned short* Bs0 = Ls[slot][1][0];
        const unsigned short* As1 = Ls[slot][0][1];
        const unsigned short* Bs1 = Ls[slot][1][1];
        s16x8 af[4], bfr[4];

        // ---- phase 0: acc[0..3] x kk0 (needs C0,C1 of t)
        if (more) { issue(nslot, 0, 0, kn); asm volatile("s_waitcnt vmcnt(6)" ::: "memory"); }
        else      {                         asm volatile("s_waitcnt vmcnt(4)" ::: "memory"); }
        __builtin_amdgcn_s_barrier();
        asm volatile("" ::: "memory");
        #pragma unroll
        for (int m = 0; m < 4; m++) af[m]  = *(const s16x8*)&As0[(wm * 128 + m * 16 + lr) * 32 + cgr];
        #pragma unroll
        for (int n = 0; n < 4; n++) bfr[n] = *(const s16x8*)&Bs0[(wn * 64 + n * 16 + lr) * 32 + cgr];
        __builtin_amdgcn_s_setprio(1);
        #pragma unroll
        for (int m = 0; m < 4; m++)
            #pragma unroll
            for (int n = 0; n < 4; n++)
                acc[m][n] = __builtin_amdgcn_mfma_f32_16x16x32_bf16(af[m], bfr[n], acc[m][n], 0, 0, 0);
        __builtin_amdgcn_s_setprio(0);
        asm volatile("" ::: "memory");
        __builtin_amdgcn_s_barrier();

        // ---- phase 1: acc[4..7] x kk0 (C0 already guaranteed; B kk0 held in regs)
        if (more) issue(nslot, 1, 0, kn);
        __builtin_amdgcn_s_barrier();
        asm volatile("" ::: "memory");
        #pragma unroll
        for (int m = 0; m < 4; m++) af[m] = *(const s16x8*)&As0[(wm * 128 + (m + 4) * 16 + lr) * 32 + cgr];
        __builtin_amdgcn_s_setprio(1);
        #pragma unroll
        for (int m = 0; m < 4; m++)
            #pragma unroll
            for (int n = 0; n < 4; n++)
                acc[m + 4][n] = __builtin_amdgcn_mfma_f32_16x16x32_bf16(af[m], bfr[n], acc[m + 4][n], 0, 0, 0);
        __builtin_amdgcn_s_setprio(0);
        asm volatile("" ::: "memory");
        __builtin_amdgcn_s_barrier();

        // ---- phase 2: acc[0..3] x kk1 (needs C2,C3 of t)
        if (more) { issue(nslot, 0, 1, kn); asm volatile("s_waitcnt vmcnt(6)" ::: "memory"); }
        else      {                         asm volatile("s_waitcnt vmcnt(0)" ::: "memory"); }
        __builtin_amdgcn_s_barrier();
        asm volatile("" ::: "memory");
        #pragma unroll
        for (int m = 0; m < 4; m++) af[m]  = *(const s16x8*)&As1[(wm * 128 + m * 16 + lr) * 32 + cgr];
        #pragma unroll
        for (int n = 0; n < 4; n++) bfr[n] = *(const s16x8*)&Bs1[(wn * 64 + n * 16 + lr) * 32 + cgr];
        __builtin_amdgcn_s_setprio(1);
        #pragma unroll
        for (int m = 0; m < 4; m++)
            #pragma unroll
            for (int n = 0; n < 4; n++)
                acc[m][n] = __builtin_amdgcn_mfma_f32_16x16x32_bf16(af[m], bfr[n], acc[m][n], 0, 0, 0);
        __builtin_amdgcn_s_setprio(0);
        asm volatile("" ::: "memory");
        __builtin_amdgcn_s_barrier();

        // ---- phase 3: acc[4..7] x kk1
        if (more) issue(nslot, 1, 1, kn);
        __builtin_amdgcn_s_barrier();
        asm volatile("" ::: "memory");
        #pragma unroll
        for (int m = 0; m < 4; m++) af[m] = *(const s16x8*)&As1[(wm * 128 + (m + 4) * 16 + lr) * 32 + cgr];
        __builtin_amdgcn_s_setprio(1);
        #pragma unroll
        for (int m = 0; m < 4; m++)
            #pragma unroll
            for (int n = 0; n < 4; n++)
                acc[m + 4][n] = __builtin_amdgcn_mfma_f32_16x16x32_bf16(af[m], bfr[n], acc[m + 4][n], 0, 0, 0);
        __builtin_amdgcn_s_setprio(0);
        asm volatile("" ::: "memory");
        __builtin_amdgcn_s_barrier();
    }

    int rbase = blockIdx.x * 256 + wm * 128;
    int cbase = blockIdx.y * 256 + wn * 64;
    #pragma unroll
    for (int am = 0; am < 8; am++)
        #pragma unroll
        for (int n = 0; n < 4; n++)
            #pragma unroll
            for (int r = 0; r < 4; r++) {
                int row = rbase + am * 16 + lg * 4 + r;
                int col = cbase + n * 16 + lr;
                float v = acc[am][n][r];
                if (OUTF32) ((float*)Cout)[(size_t)row * N + col] = v;
                else        ((unsigned short*)Cout)[(size_t)row * N + col] = f2bf(v);
            }
}

// ---------------- GEMM: 128x128 m97 structure (kept for gemm2, N=2048) ----------------
template<int OUTF32>
__global__ __launch_bounds__(256) void k_gemm_bt(const unsigned short* __restrict__ A,
                                                 const unsigned short* __restrict__ Bt,
                                                 void* __restrict__ Cout,
                                                 int M, int N, int K) {
    __shared__ unsigned short As[128 * 32];
    __shared__ unsigned short Bs[128 * 32];
    int tid = threadIdx.x;
    int lane = tid & 63;
    int wave = tid >> 6;
    int wm = wave >> 1, wn = wave & 1;
    int lr = lane & 15, lk = (lane >> 4) * 8;
    int srow = wave * 32 + (lane >> 2);
    int scol = (lane & 3) * 8;
    const unsigned short* Ag0 = A  + (size_t)(blockIdx.x * 128 + srow) * K + scol;
    const unsigned short* Ag1 = Ag0 + (size_t)16 * K;
    const unsigned short* Bg0 = Bt + (size_t)(blockIdx.y * 128 + srow) * K + scol;
    const unsigned short* Bg1 = Bg0 + (size_t)16 * K;
    unsigned short* Asw = &As[wave * 1024];
    unsigned short* Bsw = &Bs[wave * 1024];
    f32x4 acc[4][4] = {};
    for (int k0 = 0; k0 < K; k0 += 32) {
        __syncthreads();
        GLL16(Ag0 + k0, Asw);
        GLL16(Ag1 + k0, Asw + 512);
        GLL16(Bg0 + k0, Bsw);
        GLL16(Bg1 + k0, Bsw + 512);
        __syncthreads();
        s16x8 af[4], bfr[4];
        #pragma unroll
        for (int m = 0; m < 4; m++) af[m]  = *(const s16x8*)&As[(wm * 64 + m * 16 + lr) * 32 + lk];
        #pragma unroll
        for (int n = 0; n < 4; n++) bfr[n] = *(const s16x8*)&Bs[(wn * 64 + n * 16 + lr) * 32 + lk];
        #pragma unroll
        for (int m = 0; m < 4; m++)
            #pragma unroll
            for (int n = 0; n < 4; n++)
                acc[m][n] = __builtin_amdgcn_mfma_f32_16x16x32_bf16(af[m], bfr[n], acc[m][n], 0, 0, 0);
    }
    int rbase = blockIdx.x * 128 + wm * 64;
    int cbase = blockIdx.y * 128 + wn * 64;
    #pragma unroll
    for (int m = 0; m < 4; m++)
        #pragma unroll
        for (int n = 0; n < 4; n++)
            #pragma unroll
            for (int r = 0; r < 4; r++) {
                int row = rbase + m * 16 + (lane >> 4) * 4 + r;
                int col = cbase + n * 16 + lr;
                float v = acc[m][n][r];
                if (OUTF32) ((float*)Cout)[(size_t)row * N + col] = v;
                else        ((unsigned short*)Cout)[(size_t)row * N + col] = f2bf(v);
            }
}

// ---------------- fused RMSNorm + RoPE + head transpose (vectorized) ----------------
__global__ __launch_bounds__(256) void k_rms_rope(const unsigned short* __restrict__ qkv,
                                                  const float* __restrict__ qg,
                                                  const float* __restrict__ kg,
                                                  const float* __restrict__ cosc,
                                                  const float* __restrict__ sinc,
                                                  unsigned short* __restrict__ Qt,
                                                  unsigned short* __restrict__ Kt,
                                                  unsigned short* __restrict__ Vt) {
    int r = blockIdx.x;            // b*2048 + s
    int b = r >> 11;
    int s = r & 2047;
    int tid = threadIdx.x;
    int wave = tid >> 6, lane = tid & 63;
    int sl = lane >> 4;            // local segment 0..3
    int li = lane & 15;
    int d0 = li * 8;               // 0..120
    const unsigned short* row = qkv + (size_t)r * 4096;
    #pragma unroll
    for (int p = 0; p < 2; p++) {
        int seg = p * 16 + wave * 4 + sl;   // 0..31, wave-uniform type
        s16x8 raw = *(const s16x8*)(row + seg * 128 + d0);
        if (seg >= 24) {   // V: straight copy (wave-uniform branch)
            *(s16x8*)(Vt + ((size_t)(b * 8 + (seg - 24)) * 2048 + s) * 128 + d0) = raw;
            continue;
        }
        float e[8];
        #pragma unroll
        for (int j = 0; j < 8; j++) e[j] = bf2f((unsigned short)raw[j]);
        float ssq = 0.f;
        #pragma unroll
        for (int j = 0; j < 8; j++) ssq += e[j] * e[j];
        ssq += __shfl_xor(ssq, 1, 64);
        ssq += __shfl_xor(ssq, 2, 64);
        ssq += __shfl_xor(ssq, 4, 64);
        ssq += __shfl_xor(ssq, 8, 64);
        float rn = rsqrtf(ssq * (1.0f / 128.0f) + 1e-6f);
        const float* g = (seg < 16) ? qg : kg;
        float gs = (seg < 16) ? SCALE_L2E : 1.0f;
        float4 g0 = *(const float4*)(g + d0);
        float4 g1 = *(const float4*)(g + d0 + 4);
        float t[8];
        t[0] = e[0] * rn * g0.x * gs; t[1] = e[1] * rn * g0.y * gs;
        t[2] = e[2] * rn * g0.z * gs; t[3] = e[3] * rn * g0.w * gs;
        t[4] = e[4] * rn * g1.x * gs; t[5] = e[5] * rn * g1.y * gs;
        t[6] = e[6] * rn * g1.z * gs; t[7] = e[7] * rn * g1.w * gs;
        float pr[8];
        #pragma unroll
        for (int j = 0; j < 8; j++) pr[j] = __shfl_xor(t[j], 8, 64);
        int didx = d0 & 63;
        float4 c0 = *(const float4*)(cosc + (size_t)s * 64 + didx);
        float4 c1 = *(const float4*)(cosc + (size_t)s * 64 + didx + 4);
        float4 sn0 = *(const float4*)(sinc + (size_t)s * 64 + didx);
        float4 sn1 = *(const float4*)(sinc + (size_t)s * 64 + didx + 4);
        float cv[8] = {c0.x, c0.y, c0.z, c0.w, c1.x, c1.y, c1.z, c1.w};
        float sv[8] = {sn0.x, sn0.y, sn0.z, sn0.w, sn1.x, sn1.y, sn1.z, sn1.w};
        float sgn = (li < 8) ? -1.0f : 1.0f;
        s16x8 o;
        #pragma unroll
        for (int j = 0; j < 8; j++)
            o[j] = (short)f2bf(t[j] * cv[j] + sgn * pr[j] * sv[j]);
        unsigned short* dst = (seg < 16)
            ? Qt + ((size_t)(b * 16 + seg) * 2048 + s) * 128 + d0
            : Kt + ((size_t)(b * 8 + (seg - 16)) * 2048 + s) * 128 + d0;
        *(s16x8*)dst = o;
    }
}

// ---------------- causal GQA flash attention (unchanged from R7) ----------------
__global__ __launch_bounds__(512, 4) void k_attn(const unsigned short* __restrict__ Qt,
                                                 const unsigned short* __restrict__ Kt,
                                                 const unsigned short* __restrict__ Vtg,
                                                 unsigned short* __restrict__ attn) {
    __shared__ unsigned short Ks[64][136];     // K tile [kv][d], padded
    __shared__ unsigned short Vs[128][72];     // V^T tile [d][kv], padded
    __shared__ unsigned short Ps[8][16][72];   // per-wave P tile [q][kv], padded
    int bid = blockIdx.x;                  // 0..511
    int lo = bid & 255;
    int qb, bh;
    if (bid < 256) { qb = lo & 15;        bh = lo >> 4; }
    else           { qb = 15 - (lo & 15); bh = 16 + (lo >> 4); }
    int b = bh >> 4, h = bh & 15;
    int kvh = h >> 1;
    int tid = threadIdx.x;
    int lane = tid & 63, wave = tid >> 6;
    int lr = lane & 15, lg = lane >> 4;
    int q0 = qb * 128;
    const unsigned short* Qb1 = Qt + ((size_t)bh * 2048 + q0 + wave * 16) * 128;
    const unsigned short* Kbase = Kt + (size_t)(b * 8 + kvh) * 2048 * 128;
    const unsigned short* Vtb   = Vtg + (size_t)(b * 8 + kvh) * 128 * 2048;   // [d][s]
    s16x8 aq[4];
    #pragma unroll
    for (int f = 0; f < 4; f++)
        aq[f] = *(const s16x8*)(Qb1 + (size_t)lr * 128 + f * 32 + lg * 8);
    f32x4 out[8] = {};
    float m_q = -1e30f, l_q = 0.f;
    int qglob = q0 + wave * 16 + lr;
    int qlo   = q0 + wave * 16;            // wave-uniform bounds
    int qhi   = qlo + 15;
    int ntiles = 2 * qb + 2;
    int krow = tid >> 4, kcol = (tid & 15) * 8;   // K: 32 rows x 128 cols per pass, 2 passes
    int vrow = tid >> 3, vcol = (tid & 7) * 8;    // V^T: 64 rows x 64 cols per pass, 2 passes
    s16x8 kpre[2], vpre[2];
    #pragma unroll
    for (int p = 0; p < 2; p++) {
        kpre[p] = *(const s16x8*)(Kbase + (size_t)(krow + p * 32) * 128 + kcol);
        vpre[p] = *(const s16x8*)(Vtb + (size_t)(vrow + p * 64) * 2048 + vcol);
    }

    for (int t = 0; t < ntiles; t++) {
        int k0 = t * 64;
        __syncthreads();   // previous tile's LDS reads complete
        #pragma unroll
        for (int p = 0; p < 2; p++) {
            *(s16x8*)&Ks[krow + p * 32][kcol] = kpre[p];
            *(s16x8*)&Vs[vrow + p * 64][vcol] = vpre[p];
        }
        __syncthreads();
        if (t + 1 < ntiles) {
            int kn = k0 + 64;
            #pragma unroll
            for (int p = 0; p < 2; p++) {
                kpre[p] = *(const s16x8*)(Kbase + (size_t)(kn + krow + p * 32) * 128 + kcol);
                vpre[p] = *(const s16x8*)(Vtb + (size_t)(vrow + p * 64) * 2048 + kn + vcol);
            }
        }
        if (k0 <= qhi) {
            f32x4 st[4] = {};
            __builtin_amdgcn_s_setprio(1);
            #pragma unroll
            for (int sub = 0; sub < 4; sub++)
                #pragma unroll
                for (int f = 0; f < 4; f++) {
                    s16x8 bk = *(const s16x8*)&Ks[sub * 16 + lr][f * 32 + lg * 8];
                    st[sub] = __builtin_amdgcn_mfma_f32_16x16x32_bf16(bk, aq[f], st[sub], 0, 0, 0);
                }
            __builtin_amdgcn_s_setprio(0);
            float mx = -1e30f;
            if (k0 + 63 > qlo) {
                #pragma unroll
                for (int sub = 0; sub < 4; sub++)
                    #pragma unroll
                    for (int r = 0; r < 4; r++) {
                        int kv = k0 + sub * 16 + lg * 4 + r;
                        if (kv > qglob) st[sub][r] = -1e30f;
                        mx = fmaxf(mx, st[sub][r]);
                    }
            } else {
                #pragma unroll
                for (int sub = 0; sub < 4; sub++)
                    #pragma unroll
                    for (int r = 0; r < 4; r++) mx = fmaxf(mx, st[sub][r]);
            }
            mx = fmaxf(mx, __shfl_xor(mx, 16, 64));
            mx = fmaxf(mx, __shfl_xor(mx, 32, 64));
            bool defer = __all(mx <= m_q + 8.0f);
            float sf = 1.0f;
            if (!defer) {
                float mnew = fmaxf(m_q, mx);
                sf = exp2_fast(m_q - mnew);
                m_q = mnew;
            }
            float rs = 0.f;
            #pragma unroll
            for (int sub = 0; sub < 4; sub++)
                #pragma unroll
                for (int r = 0; r < 4; r++) {
                    float e = exp2_fast(st[sub][r] - m_q);
                    st[sub][r] = e;
                    rs += e;
                }
            rs += __shfl_xor(rs, 16, 64);
            rs += __shfl_xor(rs, 32, 64);
            l_q = defer ? (l_q + rs) : (l_q * sf + rs);
            #pragma unroll
            for (int sub = 0; sub < 4; sub++) {
                unsigned lop  = (unsigned)f2bf(st[sub][0]) | ((unsigned)f2bf(st[sub][1]) << 16);
                unsigned hip_ = (unsigned)f2bf(st[sub][2]) | ((unsigned)f2bf(st[sub][3]) << 16);
                uint2 w; w.x = lop; w.y = hip_;
                *(uint2*)&Ps[wave][lr][sub * 16 + lg * 4] = w;
            }
            if (!defer) {
                float sfr[4];
                #pragma unroll
                for (int r = 0; r < 4; r++) sfr[r] = __shfl(sf, lg * 4 + r, 64);
                #pragma unroll
                for (int blk = 0; blk < 8; blk++)
                    #pragma unroll
                    for (int r = 0; r < 4; r++) out[blk][r] *= sfr[r];
            }
            __builtin_amdgcn_s_setprio(1);
            #pragma unroll
            for (int ks = 0; ks < 2; ks++) {
                s16x8 ap = *(const s16x8*)&Ps[wave][lr][ks * 32 + lg * 8];
                #pragma unroll
                for (int blk = 0; blk < 8; blk++) {
                    s16x8 bv = *(const s16x8*)&Vs[blk * 16 + lr][ks * 32 + lg * 8];
                    out[blk] = __builtin_amdgcn_mfma_f32_16x16x32_bf16(ap, bv, out[blk], 0, 0, 0);
                }
            }
            __builtin_amdgcn_s_setprio(0);
        }
    }
    float linv = 1.0f / l_q;
    float inv[4];
    #pragma unroll
    for (int r = 0; r < 4; r++) inv[r] = __shfl(linv, lg * 4 + r, 64);
    #pragma unroll
    for (int blk = 0; blk < 8; blk++)
        #pragma unroll
        for (int r = 0; r < 4; r++) {
            int row = q0 + wave * 16 + lg * 4 + r;
            attn[((size_t)(b * 2048) + row) * 2048 + h * 128 + blk * 16 + lr] =
                f2bf(out[blk][r] * inv[r]);
        }
}

extern "C" void kernel_launch(void* const* d_in, const int* in_sizes, int n_in,
                              void* d_out, int out_size, void* d_ws, size_t ws_size,
                              hipStream_t stream) {
    const float* x    = (const float*)d_in[0];
    const float* wq   = (const float*)d_in[1];
    const float* wk   = (const float*)d_in[2];
    const float* wv   = (const float*)d_in[3];
    const float* wo   = (const float*)d_in[4];
    const float* qg   = (const float*)d_in[5];
    const float* kg   = (const float*)d_in[6];
    const float* cosc = (const float*)d_in[7];
    const float* sinc = (const float*)d_in[8];

    char* ws = (char*)d_ws;
    unsigned short* xb   = (unsigned short*)(ws);                 // 16 MiB  x bf16 (4096x2048)
    unsigned short* w1t  = (unsigned short*)(ws + 16777216);      // 16 MiB  [wq|wk|wv]^T (4096x2048)
    unsigned short* w2t  = (unsigned short*)(ws + 33554432);      //  8 MiB  wo^T (2048x2048)
    unsigned short* qkv  = (unsigned short*)(ws + 41943040);      // 32 MiB  (4096x4096); dead after k_rms_rope
    unsigned short* Qt   = (unsigned short*)(ws + 75497472);      // 16 MiB  (2,16,2048,128)
    unsigned short* Kt   = (unsigned short*)(ws + 92274688);      //  8 MiB  (2,8,2048,128)
    unsigned short* Vt   = (unsigned short*)(ws + 100663296);     //  8 MiB  (2,8,2048,128)
    unsigned short* attn = (unsigned short*)(ws + 109051904);     // 16 MiB  (4096x2048)
    unsigned short* Vtg  = qkv;                                   //  8 MiB  (2,8,128,2048) reuses qkv

    k_convert_x<<<4096, 256, 0, stream>>>(x, xb, 8388608);
    k_transpose_w<<<dim3(64, 64), 256, 0, stream>>>(wq, w1t, 2048, 2048, 0, 2048);
    k_transpose_w<<<dim3(64, 32), 256, 0, stream>>>(wk, w1t, 2048, 1024, 2048, 2048);
    k_transpose_w<<<dim3(64, 32), 256, 0, stream>>>(wv, w1t, 2048, 1024, 3072, 2048);
    k_transpose_w<<<dim3(64, 64), 256, 0, stream>>>(wo, w2t, 2048, 2048, 0, 2048);
    k_gemm256<0><<<dim3(16, 16), 512, 0, stream>>>(xb, w1t, qkv, 4096, 4096, 2048);
    k_rms_rope<<<4096, 256, 0, stream>>>(qkv, qg, kg, cosc, sinc, Qt, Kt, Vt);
    k_transpose_v<<<dim3(64, 4, 16), 256, 0, stream>>>(Vt, Vtg);
    k_attn<<<512, 512, 0, stream>>>(Qt, Kt, Vtg, attn);
    k_gemm_bt<1><<<dim3(32, 16), 256, 0, stream>>>(attn, w2t, d_out, 4096, 2048, 2048);
}

// Round 10
// 234.695 us; speedup vs baseline: 1.1029x; 1.0082x over previous
//
#include <hip/hip_runtime.h>
#include <hip/hip_bf16.h>

// Problem constants: B=2, S=2048, DIM=2048, H=16, KVH=8, D=128

typedef __attribute__((ext_vector_type(8))) short s16x8;   // 8 bf16 in 4 VGPRs
typedef __attribute__((ext_vector_type(4))) float f32x4;

typedef const __attribute__((address_space(1))) void* gas_t;
typedef __attribute__((address_space(3))) void* las_t;
#define GLL16(g, l) __builtin_amdgcn_global_load_lds((gas_t)(const void*)(g), (las_t)(void*)(l), 16, 0, 0)

static __device__ __forceinline__ unsigned short f2bf(float f) {
    union { float f; unsigned u; } v; v.f = f;
    unsigned r = v.u + 0x7FFF + ((v.u >> 16) & 1);   // RNE
    return (unsigned short)(r >> 16);
}
static __device__ __forceinline__ float bf2f(unsigned short h) {
    union { unsigned u; float f; } v; v.u = ((unsigned)h) << 16;
    return v.f;
}
static __device__ __forceinline__ float exp2_fast(float x) {
    float r; asm("v_exp_f32 %0, %1" : "=v"(r) : "v"(x)); return r;
}

// scale(1/sqrt(128)) * log2(e): baked into Q so softmax runs in exp2 domain
#define SCALE_L2E 0.12751744900929f

// ---------------- f32 -> bf16 elementwise convert (x) ----------------
__global__ __launch_bounds__(256) void k_convert_x(const float* __restrict__ x,
                                                   unsigned short* __restrict__ xb, int n) {
    int i = (blockIdx.x * 256 + threadIdx.x) * 8;
    if (i >= n) return;
    float4 a = *(const float4*)(x + i);
    float4 b = *(const float4*)(x + i + 4);
    s16x8 o;
    o[0] = (short)f2bf(a.x); o[1] = (short)f2bf(a.y); o[2] = (short)f2bf(a.z); o[3] = (short)f2bf(a.w);
    o[4] = (short)f2bf(b.x); o[5] = (short)f2bf(b.y); o[6] = (short)f2bf(b.z); o[7] = (short)f2bf(b.w);
    *(s16x8*)(xb + i) = o;
}

// ---------------- weight transpose f32 (K x N) -> bf16 (N x K) ----------------
__global__ __launch_bounds__(256) void k_transpose_w(const float* __restrict__ src,
                                                     unsigned short* __restrict__ dst,
                                                     int K, int N, int nbase, int dstld) {
    __shared__ float t[32][33];
    int k0 = blockIdx.x * 32, n0 = blockIdx.y * 32;
    int tx = threadIdx.x & 31, ty0 = threadIdx.x >> 5;
    for (int p = 0; p < 4; p++) {
        int ty = ty0 + p * 8;
        t[ty][tx] = src[(size_t)(k0 + ty) * N + n0 + tx];
    }
    __syncthreads();
    for (int p = 0; p < 4; p++) {
        int ty = ty0 + p * 8;
        dst[(size_t)(nbase + n0 + ty) * dstld + k0 + tx] = f2bf(t[tx][ty]);
    }
}

// ---------------- bf16 transpose: V (2048 x 128) -> Vt (128 x 2048), per (b,kvh) ----------------
__global__ __launch_bounds__(256) void k_transpose_v(const unsigned short* __restrict__ V,
                                                     unsigned short* __restrict__ Vt) {
    __shared__ unsigned short t[32][33];
    int s0 = blockIdx.x * 32, d0 = blockIdx.y * 32;
    size_t base = (size_t)blockIdx.z * 2048 * 128;
    int tx = threadIdx.x & 31, ty0 = threadIdx.x >> 5;
    for (int p = 0; p < 4; p++) {
        int ty = ty0 + p * 8;
        t[ty][tx] = V[base + (size_t)(s0 + ty) * 128 + d0 + tx];
    }
    __syncthreads();
    for (int p = 0; p < 4; p++) {
        int ty = ty0 + p * 8;
        Vt[base + (size_t)(d0 + ty) * 2048 + s0 + tx] = t[tx][ty];
    }
}

// ---------------- 256x256 GEMM v3: issue-early phases, 2 syncs/K-tile ----------------
// 512 thr (8 waves 2Mx4N). BK=64 staged as 4 chunks {A.kk0,B.kk0,A.kk1,B.kk1} of
// 256x32 (2 GLL each). Per K-tile: 4 phases; sync {vmcnt(4); s_barrier} only at
// kk0/kk1 entry. ds_reads + GLL issues precede each MFMA cluster; no trailing
// barrier, so the wave runs next phase's LDS work while the matrix pipe drains.
// Natural [256][32] chunk layout is bank-conflict-free (no swizzle).
template<int OUTF32>
__global__ __launch_bounds__(512, 2) void k_gemm256(const unsigned short* __restrict__ A,
                                                    const unsigned short* __restrict__ Bt,
                                                    void* __restrict__ Cout,
                                                    int M, int N, int K) {
    __shared__ unsigned short Ls[2][2][2][8192];   // [slot][mat A=0/B=1][kk][256*32] = 128 KiB
    int tid = threadIdx.x, lane = tid & 63, wave = tid >> 6;
    int wm = wave >> 2, wn = wave & 3;
    int lr = lane & 15, lg = lane >> 4;
    int swrow = wave * 16 + (lane >> 2);              // staging row within 128-row half
    int scol  = (lane & 3) * 8;                       // staging col (elems), linear
    const unsigned short* Ab = A  + (size_t)(blockIdx.x * 256) * K;
    const unsigned short* Bb = Bt + (size_t)(blockIdx.y * 256) * K;

    f32x4 acc[8][4] = {};
    int NK = K / 64;

    auto issue = [&](int slot, int mat, int kk, int k0) {
        const unsigned short* base = mat ? Bb : Ab;
        unsigned short* dst = &Ls[slot][mat][kk][wave * 512];
        GLL16(base + (size_t)swrow * K + k0 + kk * 32 + scol, dst);
        GLL16(base + (size_t)(swrow + 128) * K + k0 + kk * 32 + scol, dst + 4096);
    };

    // prologue: tile 0 fully staged into slot 0 (FIFO order = chunk order)
    issue(0, 0, 0, 0);
    issue(0, 1, 0, 0);
    issue(0, 0, 1, 0);
    issue(0, 1, 1, 0);

    for (int t = 0; t < NK; ++t) {
        int slot = t & 1, nslot = slot ^ 1;
        int kn = (t + 1) * 64;
        bool more = (t + 1) < NK;
        const unsigned short* As0 = Ls[slot][0][0];
        const unsigned short* Bs0 = Ls[slot][1][0];
        const unsigned short* As1 = Ls[slot][0][1];
        const unsigned short* Bs1 = Ls[slot][1][1];
        s16x8 af[4], bfr[4];

        // ==== sync: kk0 chunks of tile t arrived (retire oldest 4 GLLs) ====
        asm volatile("s_waitcnt vmcnt(4)" ::: "memory");
        __builtin_amdgcn_s_barrier();
        asm volatile("" ::: "memory");

        // ---- phase 0: acc[0..3] x kk0
        #pragma unroll
        for (int m = 0; m < 4; m++) af[m]  = *(const s16x8*)&As0[(wm * 128 + m * 16 + lr) * 32 + lg * 8];
        #pragma unroll
        for (int n = 0; n < 4; n++) bfr[n] = *(const s16x8*)&Bs0[(wn * 64 + n * 16 + lr) * 32 + lg * 8];
        if (more) issue(nslot, 0, 0, kn);
        __builtin_amdgcn_s_setprio(1);
        #pragma unroll
        for (int m = 0; m < 4; m++)
            #pragma unroll
            for (int n = 0; n < 4; n++)
                acc[m][n] = __builtin_amdgcn_mfma_f32_16x16x32_bf16(af[m], bfr[n], acc[m][n], 0, 0, 0);
        __builtin_amdgcn_s_setprio(0);

        // ---- phase 1: acc[4..7] x kk0 (B-frags reused)
        #pragma unroll
        for (int m = 0; m < 4; m++) af[m] = *(const s16x8*)&As0[(wm * 128 + (m + 4) * 16 + lr) * 32 + lg * 8];
        if (more) issue(nslot, 1, 0, kn);
        __builtin_amdgcn_s_setprio(1);
        #pragma unroll
        for (int m = 0; m < 4; m++)
            #pragma unroll
            for (int n = 0; n < 4; n++)
                acc[m + 4][n] = __builtin_amdgcn_mfma_f32_16x16x32_bf16(af[m], bfr[n], acc[m + 4][n], 0, 0, 0);
        __builtin_amdgcn_s_setprio(0);

        // ==== sync: kk1 chunks of tile t arrived ====
        if (more) asm volatile("s_waitcnt vmcnt(4)" ::: "memory");
        else      asm volatile("s_waitcnt vmcnt(0)" ::: "memory");
        __builtin_amdgcn_s_barrier();
        asm volatile("" ::: "memory");

        // ---- phase 2: acc[0..3] x kk1
        #pragma unroll
        for (int m = 0; m < 4; m++) af[m]  = *(const s16x8*)&As1[(wm * 128 + m * 16 + lr) * 32 + lg * 8];
        #pragma unroll
        for (int n = 0; n < 4; n++) bfr[n] = *(const s16x8*)&Bs1[(wn * 64 + n * 16 + lr) * 32 + lg * 8];
        if (more) issue(nslot, 0, 1, kn);
        __builtin_amdgcn_s_setprio(1);
        #pragma unroll
        for (int m = 0; m < 4; m++)
            #pragma unroll
            for (int n = 0; n < 4; n++)
                acc[m][n] = __builtin_amdgcn_mfma_f32_16x16x32_bf16(af[m], bfr[n], acc[m][n], 0, 0, 0);
        __builtin_amdgcn_s_setprio(0);

        // ---- phase 3: acc[4..7] x kk1
        #pragma unroll
        for (int m = 0; m < 4; m++) af[m] = *(const s16x8*)&As1[(wm * 128 + (m + 4) * 16 + lr) * 32 + lg * 8];
        if (more) issue(nslot, 1, 1, kn);
        __builtin_amdgcn_s_setprio(1);
        #pragma unroll
        for (int m = 0; m < 4; m++)
            #pragma unroll
            for (int n = 0; n < 4; n++)
                acc[m + 4][n] = __builtin_amdgcn_mfma_f32_16x16x32_bf16(af[m], bfr[n], acc[m + 4][n], 0, 0, 0);
        __builtin_amdgcn_s_setprio(0);
    }

    int rbase = blockIdx.x * 256 + wm * 128;
    int cbase = blockIdx.y * 256 + wn * 64;
    #pragma unroll
    for (int am = 0; am < 8; am++)
        #pragma unroll
        for (int n = 0; n < 4; n++)
            #pragma unroll
            for (int r = 0; r < 4; r++) {
                int row = rbase + am * 16 + lg * 4 + r;
                int col = cbase + n * 16 + lr;
                float v = acc[am][n][r];
                if (OUTF32) ((float*)Cout)[(size_t)row * N + col] = v;
                else        ((unsigned short*)Cout)[(size_t)row * N + col] = f2bf(v);
            }
}

// ---------------- GEMM: 128x128 m97 structure (kept for gemm2, N=2048) ----------------
template<int OUTF32>
__global__ __launch_bounds__(256) void k_gemm_bt(const unsigned short* __restrict__ A,
                                                 const unsigned short* __restrict__ Bt,
                                                 void* __restrict__ Cout,
                                                 int M, int N, int K) {
    __shared__ unsigned short As[128 * 32];
    __shared__ unsigned short Bs[128 * 32];
    int tid = threadIdx.x;
    int lane = tid & 63;
    int wave = tid >> 6;
    int wm = wave >> 1, wn = wave & 1;
    int lr = lane & 15, lk = (lane >> 4) * 8;
    int srow = wave * 32 + (lane >> 2);
    int scol = (lane & 3) * 8;
    const unsigned short* Ag0 = A  + (size_t)(blockIdx.x * 128 + srow) * K + scol;
    const unsigned short* Ag1 = Ag0 + (size_t)16 * K;
    const unsigned short* Bg0 = Bt + (size_t)(blockIdx.y * 128 + srow) * K + scol;
    const unsigned short* Bg1 = Bg0 + (size_t)16 * K;
    unsigned short* Asw = &As[wave * 1024];
    unsigned short* Bsw = &Bs[wave * 1024];
    f32x4 acc[4][4] = {};
    for (int k0 = 0; k0 < K; k0 += 32) {
        __syncthreads();
        GLL16(Ag0 + k0, Asw);
        GLL16(Ag1 + k0, Asw + 512);
        GLL16(Bg0 + k0, Bsw);
        GLL16(Bg1 + k0, Bsw + 512);
        __syncthreads();
        s16x8 af[4], bfr[4];
        #pragma unroll
        for (int m = 0; m < 4; m++) af[m]  = *(const s16x8*)&As[(wm * 64 + m * 16 + lr) * 32 + lk];
        #pragma unroll
        for (int n = 0; n < 4; n++) bfr[n] = *(const s16x8*)&Bs[(wn * 64 + n * 16 + lr) * 32 + lk];
        #pragma unroll
        for (int m = 0; m < 4; m++)
            #pragma unroll
            for (int n = 0; n < 4; n++)
                acc[m][n] = __builtin_amdgcn_mfma_f32_16x16x32_bf16(af[m], bfr[n], acc[m][n], 0, 0, 0);
    }
    int rbase = blockIdx.x * 128 + wm * 64;
    int cbase = blockIdx.y * 128 + wn * 64;
    #pragma unroll
    for (int m = 0; m < 4; m++)
        #pragma unroll
        for (int n = 0; n < 4; n++)
            #pragma unroll
            for (int r = 0; r < 4; r++) {
                int row = rbase + m * 16 + (lane >> 4) * 4 + r;
                int col = cbase + n * 16 + lr;
                float v = acc[m][n][r];
                if (OUTF32) ((float*)Cout)[(size_t)row * N + col] = v;
                else        ((unsigned short*)Cout)[(size_t)row * N + col] = f2bf(v);
            }
}

// ---------------- fused RMSNorm + RoPE + head transpose (vectorized) ----------------
__global__ __launch_bounds__(256) void k_rms_rope(const unsigned short* __restrict__ qkv,
                                                  const float* __restrict__ qg,
                                                  const float* __restrict__ kg,
                                                  const float* __restrict__ cosc,
                                                  const float* __restrict__ sinc,
                                                  unsigned short* __restrict__ Qt,
                                                  unsigned short* __restrict__ Kt,
                                                  unsigned short* __restrict__ Vt) {
    int r = blockIdx.x;            // b*2048 + s
    int b = r >> 11;
    int s = r & 2047;
    int tid = threadIdx.x;
    int wave = tid >> 6, lane = tid & 63;
    int sl = lane >> 4;            // local segment 0..3
    int li = lane & 15;
    int d0 = li * 8;               // 0..120
    const unsigned short* row = qkv + (size_t)r * 4096;
    #pragma unroll
    for (int p = 0; p < 2; p++) {
        int seg = p * 16 + wave * 4 + sl;   // 0..31, wave-uniform type
        s16x8 raw = *(const s16x8*)(row + seg * 128 + d0);
        if (seg >= 24) {   // V: straight copy (wave-uniform branch)
            *(s16x8*)(Vt + ((size_t)(b * 8 + (seg - 24)) * 2048 + s) * 128 + d0) = raw;
            continue;
        }
        float e[8];
        #pragma unroll
        for (int j = 0; j < 8; j++) e[j] = bf2f((unsigned short)raw[j]);
        float ssq = 0.f;
        #pragma unroll
        for (int j = 0; j < 8; j++) ssq += e[j] * e[j];
        ssq += __shfl_xor(ssq, 1, 64);
        ssq += __shfl_xor(ssq, 2, 64);
        ssq += __shfl_xor(ssq, 4, 64);
        ssq += __shfl_xor(ssq, 8, 64);
        float rn = rsqrtf(ssq * (1.0f / 128.0f) + 1e-6f);
        const float* g = (seg < 16) ? qg : kg;
        float gs = (seg < 16) ? SCALE_L2E : 1.0f;
        float4 g0 = *(const float4*)(g + d0);
        float4 g1 = *(const float4*)(g + d0 + 4);
        float t[8];
        t[0] = e[0] * rn * g0.x * gs; t[1] = e[1] * rn * g0.y * gs;
        t[2] = e[2] * rn * g0.z * gs; t[3] = e[3] * rn * g0.w * gs;
        t[4] = e[4] * rn * g1.x * gs; t[5] = e[5] * rn * g1.y * gs;
        t[6] = e[6] * rn * g1.z * gs; t[7] = e[7] * rn * g1.w * gs;
        float pr[8];
        #pragma unroll
        for (int j = 0; j < 8; j++) pr[j] = __shfl_xor(t[j], 8, 64);
        int didx = d0 & 63;
        float4 c0 = *(const float4*)(cosc + (size_t)s * 64 + didx);
        float4 c1 = *(const float4*)(cosc + (size_t)s * 64 + didx + 4);
        float4 sn0 = *(const float4*)(sinc + (size_t)s * 64 + didx);
        float4 sn1 = *(const float4*)(sinc + (size_t)s * 64 + didx + 4);
        float cv[8] = {c0.x, c0.y, c0.z, c0.w, c1.x, c1.y, c1.z, c1.w};
        float sv[8] = {sn0.x, sn0.y, sn0.z, sn0.w, sn1.x, sn1.y, sn1.z, sn1.w};
        float sgn = (li < 8) ? -1.0f : 1.0f;
        s16x8 o;
        #pragma unroll
        for (int j = 0; j < 8; j++)
            o[j] = (short)f2bf(t[j] * cv[j] + sgn * pr[j] * sv[j]);
        unsigned short* dst = (seg < 16)
            ? Qt + ((size_t)(b * 16 + seg) * 2048 + s) * 128 + d0
            : Kt + ((size_t)(b * 8 + (seg - 16)) * 2048 + s) * 128 + d0;
        *(s16x8*)dst = o;
    }
}

// ---------------- causal GQA flash attention (unchanged from R7) ----------------
__global__ __launch_bounds__(512, 4) void k_attn(const unsigned short* __restrict__ Qt,
                                                 const unsigned short* __restrict__ Kt,
                                                 const unsigned short* __restrict__ Vtg,
                                                 unsigned short* __restrict__ attn) {
    __shared__ unsigned short Ks[64][136];     // K tile [kv][d], padded
    __shared__ unsigned short Vs[128][72];     // V^T tile [d][kv], padded
    __shared__ unsigned short Ps[8][16][72];   // per-wave P tile [q][kv], padded
    int bid = blockIdx.x;                  // 0..511
    int lo = bid & 255;
    int qb, bh;
    if (bid < 256) { qb = lo & 15;        bh = lo >> 4; }
    else           { qb = 15 - (lo & 15); bh = 16 + (lo >> 4); }
    int b = bh >> 4, h = bh & 15;
    int kvh = h >> 1;
    int tid = threadIdx.x;
    int lane = tid & 63, wave = tid >> 6;
    int lr = lane & 15, lg = lane >> 4;
    int q0 = qb * 128;
    const unsigned short* Qb1 = Qt + ((size_t)bh * 2048 + q0 + wave * 16) * 128;
    const unsigned short* Kbase = Kt + (size_t)(b * 8 + kvh) * 2048 * 128;
    const unsigned short* Vtb   = Vtg + (size_t)(b * 8 + kvh) * 128 * 2048;   // [d][s]
    s16x8 aq[4];
    #pragma unroll
    for (int f = 0; f < 4; f++)
        aq[f] = *(const s16x8*)(Qb1 + (size_t)lr * 128 + f * 32 + lg * 8);
    f32x4 out[8] = {};
    float m_q = -1e30f, l_q = 0.f;
    int qglob = q0 + wave * 16 + lr;
    int qlo   = q0 + wave * 16;            // wave-uniform bounds
    int qhi   = qlo + 15;
    int ntiles = 2 * qb + 2;
    int krow = tid >> 4, kcol = (tid & 15) * 8;   // K: 32 rows x 128 cols per pass, 2 passes
    int vrow = tid >> 3, vcol = (tid & 7) * 8;    // V^T: 64 rows x 64 cols per pass, 2 passes
    s16x8 kpre[2], vpre[2];
    #pragma unroll
    for (int p = 0; p < 2; p++) {
        kpre[p] = *(const s16x8*)(Kbase + (size_t)(krow + p * 32) * 128 + kcol);
        vpre[p] = *(const s16x8*)(Vtb + (size_t)(vrow + p * 64) * 2048 + vcol);
    }

    for (int t = 0; t < ntiles; t++) {
        int k0 = t * 64;
        __syncthreads();   // previous tile's LDS reads complete
        #pragma unroll
        for (int p = 0; p < 2; p++) {
            *(s16x8*)&Ks[krow + p * 32][kcol] = kpre[p];
            *(s16x8*)&Vs[vrow + p * 64][vcol] = vpre[p];
        }
        __syncthreads();
        if (t + 1 < ntiles) {
            int kn = k0 + 64;
            #pragma unroll
            for (int p = 0; p < 2; p++) {
                kpre[p] = *(const s16x8*)(Kbase + (size_t)(kn + krow + p * 32) * 128 + kcol);
                vpre[p] = *(const s16x8*)(Vtb + (size_t)(vrow + p * 64) * 2048 + kn + vcol);
            }
        }
        if (k0 <= qhi) {
            f32x4 st[4] = {};
            __builtin_amdgcn_s_setprio(1);
            #pragma unroll
            for (int sub = 0; sub < 4; sub++)
                #pragma unroll
                for (int f = 0; f < 4; f++) {
                    s16x8 bk = *(const s16x8*)&Ks[sub * 16 + lr][f * 32 + lg * 8];
                    st[sub] = __builtin_amdgcn_mfma_f32_16x16x32_bf16(bk, aq[f], st[sub], 0, 0, 0);
                }
            __builtin_amdgcn_s_setprio(0);
            float mx = -1e30f;
            if (k0 + 63 > qlo) {
                #pragma unroll
                for (int sub = 0; sub < 4; sub++)
                    #pragma unroll
                    for (int r = 0; r < 4; r++) {
                        int kv = k0 + sub * 16 + lg * 4 + r;
                        if (kv > qglob) st[sub][r] = -1e30f;
                        mx = fmaxf(mx, st[sub][r]);
                    }
            } else {
                #pragma unroll
                for (int sub = 0; sub < 4; sub++)
                    #pragma unroll
                    for (int r = 0; r < 4; r++) mx = fmaxf(mx, st[sub][r]);
            }
            mx = fmaxf(mx, __shfl_xor(mx, 16, 64));
            mx = fmaxf(mx, __shfl_xor(mx, 32, 64));
            bool defer = __all(mx <= m_q + 8.0f);
            float sf = 1.0f;
            if (!defer) {
                float mnew = fmaxf(m_q, mx);
                sf = exp2_fast(m_q - mnew);
                m_q = mnew;
            }
            float rs = 0.f;
            #pragma unroll
            for (int sub = 0; sub < 4; sub++)
                #pragma unroll
                for (int r = 0; r < 4; r++) {
                    float e = exp2_fast(st[sub][r] - m_q);
                    st[sub][r] = e;
                    rs += e;
                }
            rs += __shfl_xor(rs, 16, 64);
            rs += __shfl_xor(rs, 32, 64);
            l_q = defer ? (l_q + rs) : (l_q * sf + rs);
            #pragma unroll
            for (int sub = 0; sub < 4; sub++) {
                unsigned lop  = (unsigned)f2bf(st[sub][0]) | ((unsigned)f2bf(st[sub][1]) << 16);
                unsigned hip_ = (unsigned)f2bf(st[sub][2]) | ((unsigned)f2bf(st[sub][3]) << 16);
                uint2 w; w.x = lop; w.y = hip_;
                *(uint2*)&Ps[wave][lr][sub * 16 + lg * 4] = w;
            }
            if (!defer) {
                float sfr[4];
                #pragma unroll
                for (int r = 0; r < 4; r++) sfr[r] = __shfl(sf, lg * 4 + r, 64);
                #pragma unroll
                for (int blk = 0; blk < 8; blk++)
                    #pragma unroll
                    for (int r = 0; r < 4; r++) out[blk][r] *= sfr[r];
            }
            __builtin_amdgcn_s_setprio(1);
            #pragma unroll
            for (int ks = 0; ks < 2; ks++) {
                s16x8 ap = *(const s16x8*)&Ps[wave][lr][ks * 32 + lg * 8];
                #pragma unroll
                for (int blk = 0; blk < 8; blk++) {
                    s16x8 bv = *(const s16x8*)&Vs[blk * 16 + lr][ks * 32 + lg * 8];
                    out[blk] = __builtin_amdgcn_mfma_f32_16x16x32_bf16(ap, bv, out[blk], 0, 0, 0);
                }
            }
            __builtin_amdgcn_s_setprio(0);
        }
    }
    float linv = 1.0f / l_q;
    float inv[4];
    #pragma unroll
    for (int r = 0; r < 4; r++) inv[r] = __shfl(linv, lg * 4 + r, 64);
    #pragma unroll
    for (int blk = 0; blk < 8; blk++)
        #pragma unroll
        for (int r = 0; r < 4; r++) {
            int row = q0 + wave * 16 + lg * 4 + r;
            attn[((size_t)(b * 2048) + row) * 2048 + h * 128 + blk * 16 + lr] =
                f2bf(out[blk][r] * inv[r]);
        }
}

extern "C" void kernel_launch(void* const* d_in, const int* in_sizes, int n_in,
                              void* d_out, int out_size, void* d_ws, size_t ws_size,
                              hipStream_t stream) {
    const float* x    = (const float*)d_in[0];
    const float* wq   = (const float*)d_in[1];
    const float* wk   = (const float*)d_in[2];
    const float* wv   = (const float*)d_in[3];
    const float* wo   = (const float*)d_in[4];
    const float* qg   = (const float*)d_in[5];
    const float* kg   = (const float*)d_in[6];
    const float* cosc = (const float*)d_in[7];
    const float* sinc = (const float*)d_in[8];

    char* ws = (char*)d_ws;
    unsigned short* xb   = (unsigned short*)(ws);                 // 16 MiB  x bf16 (4096x2048)
    unsigned short* w1t  = (unsigned short*)(ws + 16777216);      // 16 MiB  [wq|wk|wv]^T (4096x2048)
    unsigned short* w2t  = (unsigned short*)(ws + 33554432);      //  8 MiB  wo^T (2048x2048)
    unsigned short* qkv  = (unsigned short*)(ws + 41943040);      // 32 MiB  (4096x4096); dead after k_rms_rope
    unsigned short* Qt   = (unsigned short*)(ws + 75497472);      // 16 MiB  (2,16,2048,128)
    unsigned short* Kt   = (unsigned short*)(ws + 92274688);      //  8 MiB  (2,8,2048,128)
    unsigned short* Vt   = (unsigned short*)(ws + 100663296);     //  8 MiB  (2,8,2048,128)
    unsigned short* attn = (unsigned short*)(ws + 109051904);     // 16 MiB  (4096x2048)
    unsigned short* Vtg  = qkv;                                   //  8 MiB  (2,8,128,2048) reuses qkv

    k_convert_x<<<4096, 256, 0, stream>>>(x, xb, 8388608);
    k_transpose_w<<<dim3(64, 64), 256, 0, stream>>>(wq, w1t, 2048, 2048, 0, 2048);
    k_transpose_w<<<dim3(64, 32), 256, 0, stream>>>(wk, w1t, 2048, 1024, 2048, 2048);
    k_transpose_w<<<dim3(64, 32), 256, 0, stream>>>(wv, w1t, 2048, 1024, 3072, 2048);
    k_transpose_w<<<dim3(64, 64), 256, 0, stream>>>(wo, w2t, 2048, 2048, 0, 2048);
    k_gemm256<0><<<dim3(16, 16), 512, 0, stream>>>(xb, w1t, qkv, 4096, 4096, 2048);
    k_rms_rope<<<4096, 256, 0, stream>>>(qkv, qg, kg, cosc, sinc, Qt, Kt, Vt);
    k_transpose_v<<<dim3(64, 4, 16), 256, 0, stream>>>(Vt, Vtg);
    k_attn<<<512, 512, 0, stream>>>(Qt, Kt, Vtg, attn);
    k_gemm_bt<1><<<dim3(32, 16), 256, 0, stream>>>(attn, w2t, d_out, 4096, 2048, 2048);
}

// Round 11
// 230.134 us; speedup vs baseline: 1.1248x; 1.0198x over previous
//
#include <hip/hip_runtime.h>
#include <hip/hip_bf16.h>

// Problem constants: B=2, S=2048, DIM=2048, H=16, KVH=8, D=128

typedef __attribute__((ext_vector_type(8))) short s16x8;   // 8 bf16 in 4 VGPRs
typedef __attribute__((ext_vector_type(4))) float f32x4;
typedef __attribute__((ext_vector_type(16))) float f32x16;

typedef const __attribute__((address_space(1))) void* gas_t;
typedef __attribute__((address_space(3))) void* las_t;
#define GLL16(g, l) __builtin_amdgcn_global_load_lds((gas_t)(const void*)(g), (las_t)(void*)(l), 16, 0, 0)

static __device__ __forceinline__ unsigned short f2bf(float f) {
    union { float f; unsigned u; } v; v.f = f;
    unsigned r = v.u + 0x7FFF + ((v.u >> 16) & 1);   // RNE
    return (unsigned short)(r >> 16);
}
static __device__ __forceinline__ float bf2f(unsigned short h) {
    union { unsigned u; float f; } v; v.u = ((unsigned)h) << 16;
    return v.f;
}
static __device__ __forceinline__ float exp2_fast(float x) {
    float r; asm("v_exp_f32 %0, %1" : "=v"(r) : "v"(x)); return r;
}

// scale(1/sqrt(128)) * log2(e): baked into Q so softmax runs in exp2 domain
#define SCALE_L2E 0.12751744900929f

// ---------------- f32 -> bf16 elementwise convert (x) ----------------
__global__ __launch_bounds__(256) void k_convert_x(const float* __restrict__ x,
                                                   unsigned short* __restrict__ xb, int n) {
    int i = (blockIdx.x * 256 + threadIdx.x) * 8;
    if (i >= n) return;
    float4 a = *(const float4*)(x + i);
    float4 b = *(const float4*)(x + i + 4);
    s16x8 o;
    o[0] = (short)f2bf(a.x); o[1] = (short)f2bf(a.y); o[2] = (short)f2bf(a.z); o[3] = (short)f2bf(a.w);
    o[4] = (short)f2bf(b.x); o[5] = (short)f2bf(b.y); o[6] = (short)f2bf(b.z); o[7] = (short)f2bf(b.w);
    *(s16x8*)(xb + i) = o;
}

// ---------------- weight transpose f32 (K x N) -> bf16 (N x K) ----------------
__global__ __launch_bounds__(256) void k_transpose_w(const float* __restrict__ src,
                                                     unsigned short* __restrict__ dst,
                                                     int K, int N, int nbase, int dstld) {
    __shared__ float t[32][33];
    int k0 = blockIdx.x * 32, n0 = blockIdx.y * 32;
    int tx = threadIdx.x & 31, ty0 = threadIdx.x >> 5;
    for (int p = 0; p < 4; p++) {
        int ty = ty0 + p * 8;
        t[ty][tx] = src[(size_t)(k0 + ty) * N + n0 + tx];
    }
    __syncthreads();
    for (int p = 0; p < 4; p++) {
        int ty = ty0 + p * 8;
        dst[(size_t)(nbase + n0 + ty) * dstld + k0 + tx] = f2bf(t[tx][ty]);
    }
}

// ---------------- bf16 transpose: V (2048 x 128) -> Vt (128 x 2048), per (b,kvh) ----------------
__global__ __launch_bounds__(256) void k_transpose_v(const unsigned short* __restrict__ V,
                                                     unsigned short* __restrict__ Vt) {
    __shared__ unsigned short t[32][33];
    int s0 = blockIdx.x * 32, d0 = blockIdx.y * 32;
    size_t base = (size_t)blockIdx.z * 2048 * 128;
    int tx = threadIdx.x & 31, ty0 = threadIdx.x >> 5;
    for (int p = 0; p < 4; p++) {
        int ty = ty0 + p * 8;
        t[ty][tx] = V[base + (size_t)(s0 + ty) * 128 + d0 + tx];
    }
    __syncthreads();
    for (int p = 0; p < 4; p++) {
        int ty = ty0 + p * 8;
        Vt[base + (size_t)(d0 + ty) * 2048 + s0 + tx] = t[tx][ty];
    }
}

// ---------------- 256x256 GEMM v3 (unchanged from R9) ----------------
template<int OUTF32>
__global__ __launch_bounds__(512, 2) void k_gemm256(const unsigned short* __restrict__ A,
                                                    const unsigned short* __restrict__ Bt,
                                                    void* __restrict__ Cout,
                                                    int M, int N, int K) {
    __shared__ unsigned short Ls[2][2][2][8192];   // [slot][mat A=0/B=1][kk][256*32] = 128 KiB
    int tid = threadIdx.x, lane = tid & 63, wave = tid >> 6;
    int wm = wave >> 2, wn = wave & 3;
    int lr = lane & 15, lg = lane >> 4;
    int swrow = wave * 16 + (lane >> 2);
    int scol  = (lane & 3) * 8;
    const unsigned short* Ab = A  + (size_t)(blockIdx.x * 256) * K;
    const unsigned short* Bb = Bt + (size_t)(blockIdx.y * 256) * K;

    f32x4 acc[8][4] = {};
    int NK = K / 64;

    auto issue = [&](int slot, int mat, int kk, int k0) {
        const unsigned short* base = mat ? Bb : Ab;
        unsigned short* dst = &Ls[slot][mat][kk][wave * 512];
        GLL16(base + (size_t)swrow * K + k0 + kk * 32 + scol, dst);
        GLL16(base + (size_t)(swrow + 128) * K + k0 + kk * 32 + scol, dst + 4096);
    };

    issue(0, 0, 0, 0);
    issue(0, 1, 0, 0);
    issue(0, 0, 1, 0);
    issue(0, 1, 1, 0);

    for (int t = 0; t < NK; ++t) {
        int slot = t & 1, nslot = slot ^ 1;
        int kn = (t + 1) * 64;
        bool more = (t + 1) < NK;
        const unsigned short* As0 = Ls[slot][0][0];
        const unsigned short* Bs0 = Ls[slot][1][0];
        const unsigned short* As1 = Ls[slot][0][1];
        const unsigned short* Bs1 = Ls[slot][1][1];
        s16x8 af[4], bfr[4];

        asm volatile("s_waitcnt vmcnt(4)" ::: "memory");
        __builtin_amdgcn_s_barrier();
        asm volatile("" ::: "memory");

        #pragma unroll
        for (int m = 0; m < 4; m++) af[m]  = *(const s16x8*)&As0[(wm * 128 + m * 16 + lr) * 32 + lg * 8];
        #pragma unroll
        for (int n = 0; n < 4; n++) bfr[n] = *(const s16x8*)&Bs0[(wn * 64 + n * 16 + lr) * 32 + lg * 8];
        if (more) issue(nslot, 0, 0, kn);
        __builtin_amdgcn_s_setprio(1);
        #pragma unroll
        for (int m = 0; m < 4; m++)
            #pragma unroll
            for (int n = 0; n < 4; n++)
                acc[m][n] = __builtin_amdgcn_mfma_f32_16x16x32_bf16(af[m], bfr[n], acc[m][n], 0, 0, 0);
        __builtin_amdgcn_s_setprio(0);

        #pragma unroll
        for (int m = 0; m < 4; m++) af[m] = *(const s16x8*)&As0[(wm * 128 + (m + 4) * 16 + lr) * 32 + lg * 8];
        if (more) issue(nslot, 1, 0, kn);
        __builtin_amdgcn_s_setprio(1);
        #pragma unroll
        for (int m = 0; m < 4; m++)
            #pragma unroll
            for (int n = 0; n < 4; n++)
                acc[m + 4][n] = __builtin_amdgcn_mfma_f32_16x16x32_bf16(af[m], bfr[n], acc[m + 4][n], 0, 0, 0);
        __builtin_amdgcn_s_setprio(0);

        if (more) asm volatile("s_waitcnt vmcnt(4)" ::: "memory");
        else      asm volatile("s_waitcnt vmcnt(0)" ::: "memory");
        __builtin_amdgcn_s_barrier();
        asm volatile("" ::: "memory");

        #pragma unroll
        for (int m = 0; m < 4; m++) af[m]  = *(const s16x8*)&As1[(wm * 128 + m * 16 + lr) * 32 + lg * 8];
        #pragma unroll
        for (int n = 0; n < 4; n++) bfr[n] = *(const s16x8*)&Bs1[(wn * 64 + n * 16 + lr) * 32 + lg * 8];
        if (more) issue(nslot, 0, 1, kn);
        __builtin_amdgcn_s_setprio(1);
        #pragma unroll
        for (int m = 0; m < 4; m++)
            #pragma unroll
            for (int n = 0; n < 4; n++)
                acc[m][n] = __builtin_amdgcn_mfma_f32_16x16x32_bf16(af[m], bfr[n], acc[m][n], 0, 0, 0);
        __builtin_amdgcn_s_setprio(0);

        #pragma unroll
        for (int m = 0; m < 4; m++) af[m] = *(const s16x8*)&As1[(wm * 128 + (m + 4) * 16 + lr) * 32 + lg * 8];
        if (more) issue(nslot, 1, 1, kn);
        __builtin_amdgcn_s_setprio(1);
        #pragma unroll
        for (int m = 0; m < 4; m++)
            #pragma unroll
            for (int n = 0; n < 4; n++)
                acc[m + 4][n] = __builtin_amdgcn_mfma_f32_16x16x32_bf16(af[m], bfr[n], acc[m + 4][n], 0, 0, 0);
        __builtin_amdgcn_s_setprio(0);
    }

    int rbase = blockIdx.x * 256 + wm * 128;
    int cbase = blockIdx.y * 256 + wn * 64;
    #pragma unroll
    for (int am = 0; am < 8; am++)
        #pragma unroll
        for (int n = 0; n < 4; n++)
            #pragma unroll
            for (int r = 0; r < 4; r++) {
                int row = rbase + am * 16 + lg * 4 + r;
                int col = cbase + n * 16 + lr;
                float v = acc[am][n][r];
                if (OUTF32) ((float*)Cout)[(size_t)row * N + col] = v;
                else        ((unsigned short*)Cout)[(size_t)row * N + col] = f2bf(v);
            }
}

// ---------------- GEMM: 128x128 m97 structure (kept for gemm2, N=2048) ----------------
template<int OUTF32>
__global__ __launch_bounds__(256) void k_gemm_bt(const unsigned short* __restrict__ A,
                                                 const unsigned short* __restrict__ Bt,
                                                 void* __restrict__ Cout,
                                                 int M, int N, int K) {
    __shared__ unsigned short As[128 * 32];
    __shared__ unsigned short Bs[128 * 32];
    int tid = threadIdx.x;
    int lane = tid & 63;
    int wave = tid >> 6;
    int wm = wave >> 1, wn = wave & 1;
    int lr = lane & 15, lk = (lane >> 4) * 8;
    int srow = wave * 32 + (lane >> 2);
    int scol = (lane & 3) * 8;
    const unsigned short* Ag0 = A  + (size_t)(blockIdx.x * 128 + srow) * K + scol;
    const unsigned short* Ag1 = Ag0 + (size_t)16 * K;
    const unsigned short* Bg0 = Bt + (size_t)(blockIdx.y * 128 + srow) * K + scol;
    const unsigned short* Bg1 = Bg0 + (size_t)16 * K;
    unsigned short* Asw = &As[wave * 1024];
    unsigned short* Bsw = &Bs[wave * 1024];
    f32x4 acc[4][4] = {};
    for (int k0 = 0; k0 < K; k0 += 32) {
        __syncthreads();
        GLL16(Ag0 + k0, Asw);
        GLL16(Ag1 + k0, Asw + 512);
        GLL16(Bg0 + k0, Bsw);
        GLL16(Bg1 + k0, Bsw + 512);
        __syncthreads();
        s16x8 af[4], bfr[4];
        #pragma unroll
        for (int m = 0; m < 4; m++) af[m]  = *(const s16x8*)&As[(wm * 64 + m * 16 + lr) * 32 + lk];
        #pragma unroll
        for (int n = 0; n < 4; n++) bfr[n] = *(const s16x8*)&Bs[(wn * 64 + n * 16 + lr) * 32 + lk];
        #pragma unroll
        for (int m = 0; m < 4; m++)
            #pragma unroll
            for (int n = 0; n < 4; n++)
                acc[m][n] = __builtin_amdgcn_mfma_f32_16x16x32_bf16(af[m], bfr[n], acc[m][n], 0, 0, 0);
    }
    int rbase = blockIdx.x * 128 + wm * 64;
    int cbase = blockIdx.y * 128 + wn * 64;
    #pragma unroll
    for (int m = 0; m < 4; m++)
        #pragma unroll
        for (int n = 0; n < 4; n++)
            #pragma unroll
            for (int r = 0; r < 4; r++) {
                int row = rbase + m * 16 + (lane >> 4) * 4 + r;
                int col = cbase + n * 16 + lr;
                float v = acc[m][n][r];
                if (OUTF32) ((float*)Cout)[(size_t)row * N + col] = v;
                else        ((unsigned short*)Cout)[(size_t)row * N + col] = f2bf(v);
            }
}

// ---------------- fused RMSNorm + RoPE + head transpose (vectorized) ----------------
__global__ __launch_bounds__(256) void k_rms_rope(const unsigned short* __restrict__ qkv,
                                                  const float* __restrict__ qg,
                                                  const float* __restrict__ kg,
                                                  const float* __restrict__ cosc,
                                                  const float* __restrict__ sinc,
                                                  unsigned short* __restrict__ Qt,
                                                  unsigned short* __restrict__ Kt,
                                                  unsigned short* __restrict__ Vt) {
    int r = blockIdx.x;            // b*2048 + s
    int b = r >> 11;
    int s = r & 2047;
    int tid = threadIdx.x;
    int wave = tid >> 6, lane = tid & 63;
    int sl = lane >> 4;            // local segment 0..3
    int li = lane & 15;
    int d0 = li * 8;               // 0..120
    const unsigned short* row = qkv + (size_t)r * 4096;
    #pragma unroll
    for (int p = 0; p < 2; p++) {
        int seg = p * 16 + wave * 4 + sl;   // 0..31, wave-uniform type
        s16x8 raw = *(const s16x8*)(row + seg * 128 + d0);
        if (seg >= 24) {   // V: straight copy (wave-uniform branch)
            *(s16x8*)(Vt + ((size_t)(b * 8 + (seg - 24)) * 2048 + s) * 128 + d0) = raw;
            continue;
        }
        float e[8];
        #pragma unroll
        for (int j = 0; j < 8; j++) e[j] = bf2f((unsigned short)raw[j]);
        float ssq = 0.f;
        #pragma unroll
        for (int j = 0; j < 8; j++) ssq += e[j] * e[j];
        ssq += __shfl_xor(ssq, 1, 64);
        ssq += __shfl_xor(ssq, 2, 64);
        ssq += __shfl_xor(ssq, 4, 64);
        ssq += __shfl_xor(ssq, 8, 64);
        float rn = rsqrtf(ssq * (1.0f / 128.0f) + 1e-6f);
        const float* g = (seg < 16) ? qg : kg;
        float gs = (seg < 16) ? SCALE_L2E : 1.0f;
        float4 g0 = *(const float4*)(g + d0);
        float4 g1 = *(const float4*)(g + d0 + 4);
        float t[8];
        t[0] = e[0] * rn * g0.x * gs; t[1] = e[1] * rn * g0.y * gs;
        t[2] = e[2] * rn * g0.z * gs; t[3] = e[3] * rn * g0.w * gs;
        t[4] = e[4] * rn * g1.x * gs; t[5] = e[5] * rn * g1.y * gs;
        t[6] = e[6] * rn * g1.z * gs; t[7] = e[7] * rn * g1.w * gs;
        float pr[8];
        #pragma unroll
        for (int j = 0; j < 8; j++) pr[j] = __shfl_xor(t[j], 8, 64);
        int didx = d0 & 63;
        float4 c0 = *(const float4*)(cosc + (size_t)s * 64 + didx);
        float4 c1 = *(const float4*)(cosc + (size_t)s * 64 + didx + 4);
        float4 sn0 = *(const float4*)(sinc + (size_t)s * 64 + didx);
        float4 sn1 = *(const float4*)(sinc + (size_t)s * 64 + didx + 4);
        float cv[8] = {c0.x, c0.y, c0.z, c0.w, c1.x, c1.y, c1.z, c1.w};
        float sv[8] = {sn0.x, sn0.y, sn0.z, sn0.w, sn1.x, sn1.y, sn1.z, sn1.w};
        float sgn = (li < 8) ? -1.0f : 1.0f;
        s16x8 o;
        #pragma unroll
        for (int j = 0; j < 8; j++)
            o[j] = (short)f2bf(t[j] * cv[j] + sgn * pr[j] * sv[j]);
        unsigned short* dst = (seg < 16)
            ? Qt + ((size_t)(b * 16 + seg) * 2048 + s) * 128 + d0
            : Kt + ((size_t)(b * 8 + (seg - 16)) * 2048 + s) * 128 + d0;
        *(s16x8*)dst = o;
    }
}

// ---------------- causal GQA flash attention, 32x32 MFMA version ----------------
// 4 waves/block (256 thr), wave owns 32 q-rows (QBLK=128), KVBLK=64.
// Swapped QK^T via mfma_f32_32x32x16: lane holds 32 S values of ONE q-row
// (q = lane&31) -> 1-shuffle softmax. P bounced via per-wave Ps[32][72] in the
// C-layout-compatible arrangement; PV via 32x32x16 too. LDS bytes/FLOP halved
// vs 16x16x32 (the binding resource per R9 counters).
__global__ __launch_bounds__(256, 2) void k_attn(const unsigned short* __restrict__ Qt,
                                                 const unsigned short* __restrict__ Kt,
                                                 const unsigned short* __restrict__ Vtg,
                                                 unsigned short* __restrict__ attn) {
    __shared__ unsigned short Ks[64][136];     // K tile [kv][d], padded
    __shared__ unsigned short Vs[128][72];     // V^T tile [d][kv], padded
    __shared__ unsigned short Ps[4][32][72];   // per-wave P tile [q][kv], padded
    // duration-balanced swizzle: blocks bid and bid+256 have complementary qb
    int bid = blockIdx.x;                  // 0..511
    int lo = bid & 255;
    int qb, bh;
    if (bid < 256) { qb = lo & 15;        bh = lo >> 4; }
    else           { qb = 15 - (lo & 15); bh = 16 + (lo >> 4); }
    int b = bh >> 4, h = bh & 15;
    int kvh = h >> 1;
    int tid = threadIdx.x;
    int lane = tid & 63, wave = tid >> 6;
    int ql = lane & 31;                    // q-local (wave's 32 rows)
    int hf = lane >> 5;                    // half 0/1
    int q0 = qb * 128;
    const unsigned short* Qb    = Qt + ((size_t)bh * 2048 + q0 + wave * 32 + ql) * 128;
    const unsigned short* Kbase = Kt + (size_t)(b * 8 + kvh) * 2048 * 128;
    const unsigned short* Vtb   = Vtg + (size_t)(b * 8 + kvh) * 128 * 2048;   // [d][s]
    // Q fragments: B-operand for QK^T, lane holds Q[q=ql][d = ds*16 + hf*8 + i]
    s16x8 aq[8];
    #pragma unroll
    for (int ds = 0; ds < 8; ds++)
        aq[ds] = *(const s16x8*)(Qb + ds * 16 + hf * 8);
    f32x16 out[4] = {};                    // O[q][dblk*32 + ql], rows per r
    float m_q = -1e30f, l_q = 0.f;
    int qglob = q0 + wave * 32 + ql;
    int qlo   = q0 + wave * 32;            // wave-uniform bounds
    int qhi   = qlo + 31;
    int ntiles = 2 * qb + 2;
    // staging coords (256 threads, 4 passes each)
    int krow = tid >> 4, kcol = (tid & 15) * 8;   // K: 16 rows x 128 cols per pass
    int vrow = tid >> 3, vcol = (tid & 7) * 8;    // V^T: 32 rows x 64 cols per pass
    s16x8 kpre[4], vpre[4];
    #pragma unroll
    for (int p = 0; p < 4; p++) {
        kpre[p] = *(const s16x8*)(Kbase + (size_t)(krow + p * 16) * 128 + kcol);
        vpre[p] = *(const s16x8*)(Vtb + (size_t)(vrow + p * 32) * 2048 + vcol);
    }

    for (int t = 0; t < ntiles; t++) {
        int k0 = t * 64;
        __syncthreads();   // previous tile's LDS reads complete
        #pragma unroll
        for (int p = 0; p < 4; p++) {
            *(s16x8*)&Ks[krow + p * 16][kcol] = kpre[p];
            *(s16x8*)&Vs[vrow + p * 32][vcol] = vpre[p];
        }
        __syncthreads();
        if (t + 1 < ntiles) {
            int kn = k0 + 64;
            #pragma unroll
            for (int p = 0; p < 4; p++) {
                kpre[p] = *(const s16x8*)(Kbase + (size_t)(kn + krow + p * 16) * 128 + kcol);
                vpre[p] = *(const s16x8*)(Vtb + (size_t)(vrow + p * 32) * 2048 + kn + vcol);
            }
        }
        if (k0 <= qhi) {
            // swapped QK^T: S^T[kv][q]; A = K rows (M=kv), B = Q (N=q), K=d
            f32x16 st[2] = {};
            __builtin_amdgcn_s_setprio(1);
            #pragma unroll
            for (int sub = 0; sub < 2; sub++)
                #pragma unroll
                for (int ds = 0; ds < 8; ds++) {
                    s16x8 kf = *(const s16x8*)&Ks[sub * 32 + ql][ds * 16 + hf * 8];
                    st[sub] = __builtin_amdgcn_mfma_f32_32x32x16_bf16(kf, aq[ds], st[sub], 0, 0, 0);
                }
            __builtin_amdgcn_s_setprio(0);
            // lane holds 32 values of q-row qglob at kv = k0 + sub*32 + (r&3)+8*(r>>2)+4*hf
            float mx = -1e30f;
            if (k0 + 63 > qlo) {   // boundary tiles: apply causal mask
                #pragma unroll
                for (int sub = 0; sub < 2; sub++)
                    #pragma unroll
                    for (int r = 0; r < 16; r++) {
                        int kv = k0 + sub * 32 + (r & 3) + 8 * (r >> 2) + 4 * hf;
                        if (kv > qglob) st[sub][r] = -1e30f;
                        mx = fmaxf(mx, st[sub][r]);
                    }
            } else {
                #pragma unroll
                for (int sub = 0; sub < 2; sub++)
                    #pragma unroll
                    for (int r = 0; r < 16; r++) mx = fmaxf(mx, st[sub][r]);
            }
            mx = fmaxf(mx, __shfl_xor(mx, 32, 64));
            // T13 defer-max (exp2 domain, bound 2^8)
            bool defer = __all(mx <= m_q + 8.0f);
            float sf = 1.0f;
            if (!defer) {
                float mnew = fmaxf(m_q, mx);
                sf = exp2_fast(m_q - mnew);
                m_q = mnew;
            }
            float rs = 0.f;
            #pragma unroll
            for (int sub = 0; sub < 2; sub++)
                #pragma unroll
                for (int r = 0; r < 16; r++) {
                    float e = exp2_fast(st[sub][r] - m_q);
                    st[sub][r] = e;
                    rs += e;
                }
            rs += __shfl_xor(rs, 32, 64);
            l_q = defer ? (l_q + rs) : (l_q * sf + rs);
            // pack P -> Ps[q][kv]: group g (r=4g..4g+3) covers kv sub*32+8g+4hf..+3
            #pragma unroll
            for (int sub = 0; sub < 2; sub++)
                #pragma unroll
                for (int g = 0; g < 4; g++) {
                    unsigned lop  = (unsigned)f2bf(st[sub][4 * g + 0]) | ((unsigned)f2bf(st[sub][4 * g + 1]) << 16);
                    unsigned hip_ = (unsigned)f2bf(st[sub][4 * g + 2]) | ((unsigned)f2bf(st[sub][4 * g + 3]) << 16);
                    uint2 w; w.x = lop; w.y = hip_;
                    *(uint2*)&Ps[wave][ql][sub * 32 + g * 8 + hf * 4] = w;
                }
            if (!defer) {
                // rescale accumulator: out rows q = (r&3)+8*(r>>2)+4*hf
                float sfr[16];
                #pragma unroll
                for (int r = 0; r < 16; r++)
                    sfr[r] = __shfl(sf, (r & 3) + 8 * (r >> 2) + 4 * hf, 64);
                #pragma unroll
                for (int dblk = 0; dblk < 4; dblk++)
                    #pragma unroll
                    for (int r = 0; r < 16; r++) out[dblk][r] *= sfr[r];
            }
            // PV: O(32q x 128d) += P(32x64) V(64x128); A-frag lane = P[q=ql][kv=ks*16+hf*8+i]
            __builtin_amdgcn_s_setprio(1);
            #pragma unroll
            for (int ks = 0; ks < 4; ks++) {
                s16x8 pf = *(const s16x8*)&Ps[wave][ql][ks * 16 + hf * 8];
                #pragma unroll
                for (int dblk = 0; dblk < 4; dblk++) {
                    s16x8 vf = *(const s16x8*)&Vs[dblk * 32 + ql][ks * 16 + hf * 8];
                    out[dblk] = __builtin_amdgcn_mfma_f32_32x32x16_bf16(pf, vf, out[dblk], 0, 0, 0);
                }
            }
            __builtin_amdgcn_s_setprio(0);
        }
    }
    float linv = 1.0f / l_q;
    float inv[16];
    #pragma unroll
    for (int r = 0; r < 16; r++)
        inv[r] = __shfl(linv, (r & 3) + 8 * (r >> 2) + 4 * hf, 64);
    #pragma unroll
    for (int dblk = 0; dblk < 4; dblk++)
        #pragma unroll
        for (int r = 0; r < 16; r++) {
            int row = q0 + wave * 32 + (r & 3) + 8 * (r >> 2) + 4 * hf;
            attn[((size_t)(b * 2048) + row) * 2048 + h * 128 + dblk * 32 + ql] =
                f2bf(out[dblk][r] * inv[r]);
        }
}

extern "C" void kernel_launch(void* const* d_in, const int* in_sizes, int n_in,
                              void* d_out, int out_size, void* d_ws, size_t ws_size,
                              hipStream_t stream) {
    const float* x    = (const float*)d_in[0];
    const float* wq   = (const float*)d_in[1];
    const float* wk   = (const float*)d_in[2];
    const float* wv   = (const float*)d_in[3];
    const float* wo   = (const float*)d_in[4];
    const float* qg   = (const float*)d_in[5];
    const float* kg   = (const float*)d_in[6];
    const float* cosc = (const float*)d_in[7];
    const float* sinc = (const float*)d_in[8];

    char* ws = (char*)d_ws;
    unsigned short* xb   = (unsigned short*)(ws);                 // 16 MiB  x bf16 (4096x2048)
    unsigned short* w1t  = (unsigned short*)(ws + 16777216);      // 16 MiB  [wq|wk|wv]^T (4096x2048)
    unsigned short* w2t  = (unsigned short*)(ws + 33554432);      //  8 MiB  wo^T (2048x2048)
    unsigned short* qkv  = (unsigned short*)(ws + 41943040);      // 32 MiB  (4096x4096); dead after k_rms_rope
    unsigned short* Qt   = (unsigned short*)(ws + 75497472);      // 16 MiB  (2,16,2048,128)
    unsigned short* Kt   = (unsigned short*)(ws + 92274688);      //  8 MiB  (2,8,2048,128)
    unsigned short* Vt   = (unsigned short*)(ws + 100663296);     //  8 MiB  (2,8,2048,128)
    unsigned short* attn = (unsigned short*)(ws + 109051904);     // 16 MiB  (4096x2048)
    unsigned short* Vtg  = qkv;                                   //  8 MiB  (2,8,128,2048) reuses qkv

    k_convert_x<<<4096, 256, 0, stream>>>(x, xb, 8388608);
    k_transpose_w<<<dim3(64, 64), 256, 0, stream>>>(wq, w1t, 2048, 2048, 0, 2048);
    k_transpose_w<<<dim3(64, 32), 256, 0, stream>>>(wk, w1t, 2048, 1024, 2048, 2048);
    k_transpose_w<<<dim3(64, 32), 256, 0, stream>>>(wv, w1t, 2048, 1024, 3072, 2048);
    k_transpose_w<<<dim3(64, 64), 256, 0, stream>>>(wo, w2t, 2048, 2048, 0, 2048);
    k_gemm256<0><<<dim3(16, 16), 512, 0, stream>>>(xb, w1t, qkv, 4096, 4096, 2048);
    k_rms_rope<<<4096, 256, 0, stream>>>(qkv, qg, kg, cosc, sinc, Qt, Kt, Vt);
    k_transpose_v<<<dim3(64, 4, 16), 256, 0, stream>>>(Vt, Vtg);
    k_attn<<<512, 256, 0, stream>>>(Qt, Kt, Vtg, attn);
    k_gemm_bt<1><<<dim3(32, 16), 256, 0, stream>>>(attn, w2t, d_out, 4096, 2048, 2048);
}

// Round 12
// 229.028 us; speedup vs baseline: 1.1302x; 1.0048x over previous
//
#include <hip/hip_runtime.h>
#include <hip/hip_bf16.h>

// Problem constants: B=2, S=2048, DIM=2048, H=16, KVH=8, D=128

typedef __attribute__((ext_vector_type(8))) short s16x8;   // 8 bf16 in 4 VGPRs
typedef __attribute__((ext_vector_type(4))) float f32x4;
typedef __attribute__((ext_vector_type(16))) float f32x16;

typedef const __attribute__((address_space(1))) void* gas_t;
typedef __attribute__((address_space(3))) void* las_t;
#define GLL16(g, l) __builtin_amdgcn_global_load_lds((gas_t)(const void*)(g), (las_t)(void*)(l), 16, 0, 0)

static __device__ __forceinline__ unsigned short f2bf(float f) {
    union { float f; unsigned u; } v; v.f = f;
    unsigned r = v.u + 0x7FFF + ((v.u >> 16) & 1);   // RNE
    return (unsigned short)(r >> 16);
}
static __device__ __forceinline__ float bf2f(unsigned short h) {
    union { unsigned u; float f; } v; v.u = ((unsigned)h) << 16;
    return v.f;
}
static __device__ __forceinline__ float exp2_fast(float x) {
    float r; asm("v_exp_f32 %0, %1" : "=v"(r) : "v"(x)); return r;
}
static __device__ __forceinline__ unsigned cvt_pk_bf16(float a, float b) {
    unsigned r; asm("v_cvt_pk_bf16_f32 %0, %1, %2" : "=v"(r) : "v"(a), "v"(b)); return r;
}

// scale(1/sqrt(128)) * log2(e): baked into Q so softmax runs in exp2 domain
#define SCALE_L2E 0.12751744900929f

// ---------------- f32 -> bf16 elementwise convert (x) ----------------
__global__ __launch_bounds__(256) void k_convert_x(const float* __restrict__ x,
                                                   unsigned short* __restrict__ xb, int n) {
    int i = (blockIdx.x * 256 + threadIdx.x) * 8;
    if (i >= n) return;
    float4 a = *(const float4*)(x + i);
    float4 b = *(const float4*)(x + i + 4);
    s16x8 o;
    o[0] = (short)f2bf(a.x); o[1] = (short)f2bf(a.y); o[2] = (short)f2bf(a.z); o[3] = (short)f2bf(a.w);
    o[4] = (short)f2bf(b.x); o[5] = (short)f2bf(b.y); o[6] = (short)f2bf(b.z); o[7] = (short)f2bf(b.w);
    *(s16x8*)(xb + i) = o;
}

// ---------------- weight transpose f32 (K x N) -> bf16 (N x K) ----------------
__global__ __launch_bounds__(256) void k_transpose_w(const float* __restrict__ src,
                                                     unsigned short* __restrict__ dst,
                                                     int K, int N, int nbase, int dstld) {
    __shared__ float t[32][33];
    int k0 = blockIdx.x * 32, n0 = blockIdx.y * 32;
    int tx = threadIdx.x & 31, ty0 = threadIdx.x >> 5;
    for (int p = 0; p < 4; p++) {
        int ty = ty0 + p * 8;
        t[ty][tx] = src[(size_t)(k0 + ty) * N + n0 + tx];
    }
    __syncthreads();
    for (int p = 0; p < 4; p++) {
        int ty = ty0 + p * 8;
        dst[(size_t)(nbase + n0 + ty) * dstld + k0 + tx] = f2bf(t[tx][ty]);
    }
}

// ---------------- bf16 transpose: V (2048 x 128) -> Vt (128 x 2048), per (b,kvh) ----------------
__global__ __launch_bounds__(256) void k_transpose_v(const unsigned short* __restrict__ V,
                                                     unsigned short* __restrict__ Vt) {
    __shared__ unsigned short t[32][33];
    int s0 = blockIdx.x * 32, d0 = blockIdx.y * 32;
    size_t base = (size_t)blockIdx.z * 2048 * 128;
    int tx = threadIdx.x & 31, ty0 = threadIdx.x >> 5;
    for (int p = 0; p < 4; p++) {
        int ty = ty0 + p * 8;
        t[ty][tx] = V[base + (size_t)(s0 + ty) * 128 + d0 + tx];
    }
    __syncthreads();
    for (int p = 0; p < 4; p++) {
        int ty = ty0 + p * 8;
        Vt[base + (size_t)(d0 + ty) * 2048 + s0 + tx] = t[tx][ty];
    }
}

// ---------------- 256x256 GEMM v4: m201-style barrier-paired phases ----------------
// 512 thr (8 waves 2Mx4N). BK=64 as 4 chunks {A.kk0,B.kk0,A.kk1,B.kk1} of 256x32
// (one "pair" = 2 GLL each). Phase p of tile t issues pair p of tile t+1.
// vmcnt(6) after the issues at phases 0,2 leaves exactly 3 pairs in flight and
// guarantees the kk-chunk consumed by the upcoming post-barrier ds_reads landed.
// Per phase: {issue, [vmcnt], barrier, ds_read 4-8 b128, lgkmcnt(0)+sched_barrier,
// setprio(1), 16 MFMA, setprio(0), barrier}. [256][32] chunks: bank-conflict-free.
template<int OUTF32>
__global__ __launch_bounds__(512, 2) void k_gemm256(const unsigned short* __restrict__ A,
                                                    const unsigned short* __restrict__ Bt,
                                                    void* __restrict__ Cout,
                                                    int M, int N, int K) {
    __shared__ unsigned short Ls[2][2][2][8192];   // [slot][mat A=0/B=1][kk][256*32] = 128 KiB
    int tid = threadIdx.x, lane = tid & 63, wave = tid >> 6;
    int wm = wave >> 2, wn = wave & 3;
    int lr = lane & 15, lg = lane >> 4;
    int swrow = wave * 16 + (lane >> 2);              // staging row within 128-row half
    int scol  = (lane & 3) * 8;                       // staging col (elems), linear
    const unsigned short* Ab = A  + (size_t)(blockIdx.x * 256) * K;
    const unsigned short* Bb = Bt + (size_t)(blockIdx.y * 256) * K;

    f32x4 acc[8][4] = {};
    int NK = K / 64;

    auto issue = [&](int slot, int mat, int kk, int k0) {
        const unsigned short* base = mat ? Bb : Ab;
        unsigned short* dst = &Ls[slot][mat][kk][wave * 512];
        GLL16(base + (size_t)swrow * K + k0 + kk * 32 + scol, dst);
        GLL16(base + (size_t)(swrow + 128) * K + k0 + kk * 32 + scol, dst + 4096);
    };

    // prologue: tile 0 fully staged into slot 0, pair order A.kk0,B.kk0,A.kk1,B.kk1
    issue(0, 0, 0, 0);
    issue(0, 1, 0, 0);
    issue(0, 0, 1, 0);
    issue(0, 1, 1, 0);

    for (int t = 0; t < NK; ++t) {
        int slot = t & 1, nslot = slot ^ 1;
        int kn = (t + 1) * 64;
        bool more = (t + 1) < NK;
        const unsigned short* As0 = Ls[slot][0][0];
        const unsigned short* Bs0 = Ls[slot][1][0];
        const unsigned short* As1 = Ls[slot][0][1];
        const unsigned short* Bs1 = Ls[slot][1][1];
        s16x8 af[4], bfr[4];

        // ---- phase 0: kk0, m0-3 ----
        if (more) { issue(nslot, 0, 0, kn); asm volatile("s_waitcnt vmcnt(6)" ::: "memory"); }
        else      {                         asm volatile("s_waitcnt vmcnt(4)" ::: "memory"); }
        __builtin_amdgcn_s_barrier();
        asm volatile("" ::: "memory");
        #pragma unroll
        for (int m = 0; m < 4; m++) af[m]  = *(const s16x8*)&As0[(wm * 128 + m * 16 + lr) * 32 + lg * 8];
        #pragma unroll
        for (int n = 0; n < 4; n++) bfr[n] = *(const s16x8*)&Bs0[(wn * 64 + n * 16 + lr) * 32 + lg * 8];
        asm volatile("s_waitcnt lgkmcnt(0)" ::: "memory");
        __builtin_amdgcn_sched_barrier(0);
        __builtin_amdgcn_s_setprio(1);
        #pragma unroll
        for (int m = 0; m < 4; m++)
            #pragma unroll
            for (int n = 0; n < 4; n++)
                acc[m][n] = __builtin_amdgcn_mfma_f32_16x16x32_bf16(af[m], bfr[n], acc[m][n], 0, 0, 0);
        __builtin_amdgcn_s_setprio(0);
        __builtin_amdgcn_s_barrier();

        // ---- phase 1: kk0, m4-7 (bfr reused) ----
        if (more) issue(nslot, 1, 0, kn);
        __builtin_amdgcn_s_barrier();
        asm volatile("" ::: "memory");
        #pragma unroll
        for (int m = 0; m < 4; m++) af[m] = *(const s16x8*)&As0[(wm * 128 + (m + 4) * 16 + lr) * 32 + lg * 8];
        asm volatile("s_waitcnt lgkmcnt(0)" ::: "memory");
        __builtin_amdgcn_sched_barrier(0);
        __builtin_amdgcn_s_setprio(1);
        #pragma unroll
        for (int m = 0; m < 4; m++)
            #pragma unroll
            for (int n = 0; n < 4; n++)
                acc[m + 4][n] = __builtin_amdgcn_mfma_f32_16x16x32_bf16(af[m], bfr[n], acc[m + 4][n], 0, 0, 0);
        __builtin_amdgcn_s_setprio(0);
        __builtin_amdgcn_s_barrier();

        // ---- phase 2: kk1, m0-3 ----
        if (more) { issue(nslot, 0, 1, kn); asm volatile("s_waitcnt vmcnt(6)" ::: "memory"); }
        else      {                         asm volatile("s_waitcnt vmcnt(0)" ::: "memory"); }
        __builtin_amdgcn_s_barrier();
        asm volatile("" ::: "memory");
        #pragma unroll
        for (int m = 0; m < 4; m++) af[m]  = *(const s16x8*)&As1[(wm * 128 + m * 16 + lr) * 32 + lg * 8];
        #pragma unroll
        for (int n = 0; n < 4; n++) bfr[n] = *(const s16x8*)&Bs1[(wn * 64 + n * 16 + lr) * 32 + lg * 8];
        asm volatile("s_waitcnt lgkmcnt(0)" ::: "memory");
        __builtin_amdgcn_sched_barrier(0);
        __builtin_amdgcn_s_setprio(1);
        #pragma unroll
        for (int m = 0; m < 4; m++)
            #pragma unroll
            for (int n = 0; n < 4; n++)
                acc[m][n] = __builtin_amdgcn_mfma_f32_16x16x32_bf16(af[m], bfr[n], acc[m][n], 0, 0, 0);
        __builtin_amdgcn_s_setprio(0);
        __builtin_amdgcn_s_barrier();

        // ---- phase 3: kk1, m4-7 ----
        if (more) issue(nslot, 1, 1, kn);
        __builtin_amdgcn_s_barrier();
        asm volatile("" ::: "memory");
        #pragma unroll
        for (int m = 0; m < 4; m++) af[m] = *(const s16x8*)&As1[(wm * 128 + (m + 4) * 16 + lr) * 32 + lg * 8];
        asm volatile("s_waitcnt lgkmcnt(0)" ::: "memory");
        __builtin_amdgcn_sched_barrier(0);
        __builtin_amdgcn_s_setprio(1);
        #pragma unroll
        for (int m = 0; m < 4; m++)
            #pragma unroll
            for (int n = 0; n < 4; n++)
                acc[m + 4][n] = __builtin_amdgcn_mfma_f32_16x16x32_bf16(af[m], bfr[n], acc[m + 4][n], 0, 0, 0);
        __builtin_amdgcn_s_setprio(0);
        __builtin_amdgcn_s_barrier();
    }

    int rbase = blockIdx.x * 256 + wm * 128;
    int cbase = blockIdx.y * 256 + wn * 64;
    #pragma unroll
    for (int am = 0; am < 8; am++)
        #pragma unroll
        for (int n = 0; n < 4; n++)
            #pragma unroll
            for (int r = 0; r < 4; r++) {
                int row = rbase + am * 16 + lg * 4 + r;
                int col = cbase + n * 16 + lr;
                float v = acc[am][n][r];
                if (OUTF32) ((float*)Cout)[(size_t)row * N + col] = v;
                else        ((unsigned short*)Cout)[(size_t)row * N + col] = f2bf(v);
            }
}

// ---------------- GEMM: 128x128 m97 structure (kept for gemm2, N=2048) ----------------
template<int OUTF32>
__global__ __launch_bounds__(256) void k_gemm_bt(const unsigned short* __restrict__ A,
                                                 const unsigned short* __restrict__ Bt,
                                                 void* __restrict__ Cout,
                                                 int M, int N, int K) {
    __shared__ unsigned short As[128 * 32];
    __shared__ unsigned short Bs[128 * 32];
    int tid = threadIdx.x;
    int lane = tid & 63;
    int wave = tid >> 6;
    int wm = wave >> 1, wn = wave & 1;
    int lr = lane & 15, lk = (lane >> 4) * 8;
    int srow = wave * 32 + (lane >> 2);
    int scol = (lane & 3) * 8;
    const unsigned short* Ag0 = A  + (size_t)(blockIdx.x * 128 + srow) * K + scol;
    const unsigned short* Ag1 = Ag0 + (size_t)16 * K;
    const unsigned short* Bg0 = Bt + (size_t)(blockIdx.y * 128 + srow) * K + scol;
    const unsigned short* Bg1 = Bg0 + (size_t)16 * K;
    unsigned short* Asw = &As[wave * 1024];
    unsigned short* Bsw = &Bs[wave * 1024];
    f32x4 acc[4][4] = {};
    for (int k0 = 0; k0 < K; k0 += 32) {
        __syncthreads();
        GLL16(Ag0 + k0, Asw);
        GLL16(Ag1 + k0, Asw + 512);
        GLL16(Bg0 + k0, Bsw);
        GLL16(Bg1 + k0, Bsw + 512);
        __syncthreads();
        s16x8 af[4], bfr[4];
        #pragma unroll
        for (int m = 0; m < 4; m++) af[m]  = *(const s16x8*)&As[(wm * 64 + m * 16 + lr) * 32 + lk];
        #pragma unroll
        for (int n = 0; n < 4; n++) bfr[n] = *(const s16x8*)&Bs[(wn * 64 + n * 16 + lr) * 32 + lk];
        #pragma unroll
        for (int m = 0; m < 4; m++)
            #pragma unroll
            for (int n = 0; n < 4; n++)
                acc[m][n] = __builtin_amdgcn_mfma_f32_16x16x32_bf16(af[m], bfr[n], acc[m][n], 0, 0, 0);
    }
    int rbase = blockIdx.x * 128 + wm * 64;
    int cbase = blockIdx.y * 128 + wn * 64;
    #pragma unroll
    for (int m = 0; m < 4; m++)
        #pragma unroll
        for (int n = 0; n < 4; n++)
            #pragma unroll
            for (int r = 0; r < 4; r++) {
                int row = rbase + m * 16 + (lane >> 4) * 4 + r;
                int col = cbase + n * 16 + lr;
                float v = acc[m][n][r];
                if (OUTF32) ((float*)Cout)[(size_t)row * N + col] = v;
                else        ((unsigned short*)Cout)[(size_t)row * N + col] = f2bf(v);
            }
}

// ---------------- fused RMSNorm + RoPE + head transpose (vectorized) ----------------
__global__ __launch_bounds__(256) void k_rms_rope(const unsigned short* __restrict__ qkv,
                                                  const float* __restrict__ qg,
                                                  const float* __restrict__ kg,
                                                  const float* __restrict__ cosc,
                                                  const float* __restrict__ sinc,
                                                  unsigned short* __restrict__ Qt,
                                                  unsigned short* __restrict__ Kt,
                                                  unsigned short* __restrict__ Vt) {
    int r = blockIdx.x;            // b*2048 + s
    int b = r >> 11;
    int s = r & 2047;
    int tid = threadIdx.x;
    int wave = tid >> 6, lane = tid & 63;
    int sl = lane >> 4;            // local segment 0..3
    int li = lane & 15;
    int d0 = li * 8;               // 0..120
    const unsigned short* row = qkv + (size_t)r * 4096;
    #pragma unroll
    for (int p = 0; p < 2; p++) {
        int seg = p * 16 + wave * 4 + sl;   // 0..31, wave-uniform type
        s16x8 raw = *(const s16x8*)(row + seg * 128 + d0);
        if (seg >= 24) {   // V: straight copy (wave-uniform branch)
            *(s16x8*)(Vt + ((size_t)(b * 8 + (seg - 24)) * 2048 + s) * 128 + d0) = raw;
            continue;
        }
        float e[8];
        #pragma unroll
        for (int j = 0; j < 8; j++) e[j] = bf2f((unsigned short)raw[j]);
        float ssq = 0.f;
        #pragma unroll
        for (int j = 0; j < 8; j++) ssq += e[j] * e[j];
        ssq += __shfl_xor(ssq, 1, 64);
        ssq += __shfl_xor(ssq, 2, 64);
        ssq += __shfl_xor(ssq, 4, 64);
        ssq += __shfl_xor(ssq, 8, 64);
        float rn = rsqrtf(ssq * (1.0f / 128.0f) + 1e-6f);
        const float* g = (seg < 16) ? qg : kg;
        float gs = (seg < 16) ? SCALE_L2E : 1.0f;
        float4 g0 = *(const float4*)(g + d0);
        float4 g1 = *(const float4*)(g + d0 + 4);
        float t[8];
        t[0] = e[0] * rn * g0.x * gs; t[1] = e[1] * rn * g0.y * gs;
        t[2] = e[2] * rn * g0.z * gs; t[3] = e[3] * rn * g0.w * gs;
        t[4] = e[4] * rn * g1.x * gs; t[5] = e[5] * rn * g1.y * gs;
        t[6] = e[6] * rn * g1.z * gs; t[7] = e[7] * rn * g1.w * gs;
        float pr[8];
        #pragma unroll
        for (int j = 0; j < 8; j++) pr[j] = __shfl_xor(t[j], 8, 64);
        int didx = d0 & 63;
        float4 c0 = *(const float4*)(cosc + (size_t)s * 64 + didx);
        float4 c1 = *(const float4*)(cosc + (size_t)s * 64 + didx + 4);
        float4 sn0 = *(const float4*)(sinc + (size_t)s * 64 + didx);
        float4 sn1 = *(const float4*)(sinc + (size_t)s * 64 + didx + 4);
        float cv[8] = {c0.x, c0.y, c0.z, c0.w, c1.x, c1.y, c1.z, c1.w};
        float sv[8] = {sn0.x, sn0.y, sn0.z, sn0.w, sn1.x, sn1.y, sn1.z, sn1.w};
        float sgn = (li < 8) ? -1.0f : 1.0f;
        s16x8 o;
        #pragma unroll
        for (int j = 0; j < 8; j++)
            o[j] = (short)f2bf(t[j] * cv[j] + sgn * pr[j] * sv[j]);
        unsigned short* dst = (seg < 16)
            ? Qt + ((size_t)(b * 16 + seg) * 2048 + s) * 128 + d0
            : Kt + ((size_t)(b * 8 + (seg - 16)) * 2048 + s) * 128 + d0;
        *(s16x8*)dst = o;
    }
}

// ---------------- causal GQA flash attention, 32x32 MFMA (R10 + cvt_pk pack) ----------------
__global__ __launch_bounds__(256, 2) void k_attn(const unsigned short* __restrict__ Qt,
                                                 const unsigned short* __restrict__ Kt,
                                                 const unsigned short* __restrict__ Vtg,
                                                 unsigned short* __restrict__ attn) {
    __shared__ unsigned short Ks[64][136];     // K tile [kv][d], padded
    __shared__ unsigned short Vs[128][72];     // V^T tile [d][kv], padded
    __shared__ unsigned short Ps[4][32][72];   // per-wave P tile [q][kv], padded
    int bid = blockIdx.x;                  // 0..511
    int lo = bid & 255;
    int qb, bh;
    if (bid < 256) { qb = lo & 15;        bh = lo >> 4; }
    else           { qb = 15 - (lo & 15); bh = 16 + (lo >> 4); }
    int b = bh >> 4, h = bh & 15;
    int kvh = h >> 1;
    int tid = threadIdx.x;
    int lane = tid & 63, wave = tid >> 6;
    int ql = lane & 31;                    // q-local (wave's 32 rows)
    int hf = lane >> 5;                    // half 0/1
    int q0 = qb * 128;
    const unsigned short* Qb    = Qt + ((size_t)bh * 2048 + q0 + wave * 32 + ql) * 128;
    const unsigned short* Kbase = Kt + (size_t)(b * 8 + kvh) * 2048 * 128;
    const unsigned short* Vtb   = Vtg + (size_t)(b * 8 + kvh) * 128 * 2048;   // [d][s]
    s16x8 aq[8];
    #pragma unroll
    for (int ds = 0; ds < 8; ds++)
        aq[ds] = *(const s16x8*)(Qb + ds * 16 + hf * 8);
    f32x16 out[4] = {};
    float m_q = -1e30f, l_q = 0.f;
    int qglob = q0 + wave * 32 + ql;
    int qlo   = q0 + wave * 32;            // wave-uniform bounds
    int qhi   = qlo + 31;
    int ntiles = 2 * qb + 2;
    int krow = tid >> 4, kcol = (tid & 15) * 8;   // K: 16 rows x 128 cols per pass
    int vrow = tid >> 3, vcol = (tid & 7) * 8;    // V^T: 32 rows x 64 cols per pass
    s16x8 kpre[4], vpre[4];
    #pragma unroll
    for (int p = 0; p < 4; p++) {
        kpre[p] = *(const s16x8*)(Kbase + (size_t)(krow + p * 16) * 128 + kcol);
        vpre[p] = *(const s16x8*)(Vtb + (size_t)(vrow + p * 32) * 2048 + vcol);
    }

    for (int t = 0; t < ntiles; t++) {
        int k0 = t * 64;
        __syncthreads();   // previous tile's LDS reads complete
        #pragma unroll
        for (int p = 0; p < 4; p++) {
            *(s16x8*)&Ks[krow + p * 16][kcol] = kpre[p];
            *(s16x8*)&Vs[vrow + p * 32][vcol] = vpre[p];
        }
        __syncthreads();
        if (t + 1 < ntiles) {
            int kn = k0 + 64;
            #pragma unroll
            for (int p = 0; p < 4; p++) {
                kpre[p] = *(const s16x8*)(Kbase + (size_t)(kn + krow + p * 16) * 128 + kcol);
                vpre[p] = *(const s16x8*)(Vtb + (size_t)(vrow + p * 32) * 2048 + kn + vcol);
            }
        }
        if (k0 <= qhi) {
            f32x16 st[2] = {};
            __builtin_amdgcn_s_setprio(1);
            #pragma unroll
            for (int sub = 0; sub < 2; sub++)
                #pragma unroll
                for (int ds = 0; ds < 8; ds++) {
                    s16x8 kf = *(const s16x8*)&Ks[sub * 32 + ql][ds * 16 + hf * 8];
                    st[sub] = __builtin_amdgcn_mfma_f32_32x32x16_bf16(kf, aq[ds], st[sub], 0, 0, 0);
                }
            __builtin_amdgcn_s_setprio(0);
            float mx = -1e30f;
            if (k0 + 63 > qlo) {   // boundary tiles: apply causal mask
                #pragma unroll
                for (int sub = 0; sub < 2; sub++)
                    #pragma unroll
                    for (int r = 0; r < 16; r++) {
                        int kv = k0 + sub * 32 + (r & 3) + 8 * (r >> 2) + 4 * hf;
                        if (kv > qglob) st[sub][r] = -1e30f;
                        mx = fmaxf(mx, st[sub][r]);
                    }
            } else {
                #pragma unroll
                for (int sub = 0; sub < 2; sub++)
                    #pragma unroll
                    for (int r = 0; r < 16; r++) mx = fmaxf(mx, st[sub][r]);
            }
            mx = fmaxf(mx, __shfl_xor(mx, 32, 64));
            bool defer = __all(mx <= m_q + 8.0f);
            float sf = 1.0f;
            if (!defer) {
                float mnew = fmaxf(m_q, mx);
                sf = exp2_fast(m_q - mnew);
                m_q = mnew;
            }
            float rs = 0.f;
            #pragma unroll
            for (int sub = 0; sub < 2; sub++)
                #pragma unroll
                for (int r = 0; r < 16; r++) {
                    float e = exp2_fast(st[sub][r] - m_q);
                    st[sub][r] = e;
                    rs += e;
                }
            rs += __shfl_xor(rs, 32, 64);
            l_q = defer ? (l_q + rs) : (l_q * sf + rs);
            // pack P -> Ps[q][kv] via hardware cvt_pk (RNE)
            #pragma unroll
            for (int sub = 0; sub < 2; sub++)
                #pragma unroll
                for (int g = 0; g < 4; g++) {
                    uint2 w;
                    w.x = cvt_pk_bf16(st[sub][4 * g + 0], st[sub][4 * g + 1]);
                    w.y = cvt_pk_bf16(st[sub][4 * g + 2], st[sub][4 * g + 3]);
                    *(uint2*)&Ps[wave][ql][sub * 32 + g * 8 + hf * 4] = w;
                }
            if (!defer) {
                float sfr[16];
                #pragma unroll
                for (int r = 0; r < 16; r++)
                    sfr[r] = __shfl(sf, (r & 3) + 8 * (r >> 2) + 4 * hf, 64);
                #pragma unroll
                for (int dblk = 0; dblk < 4; dblk++)
                    #pragma unroll
                    for (int r = 0; r < 16; r++) out[dblk][r] *= sfr[r];
            }
            __builtin_amdgcn_s_setprio(1);
            #pragma unroll
            for (int ks = 0; ks < 4; ks++) {
                s16x8 pf = *(const s16x8*)&Ps[wave][ql][ks * 16 + hf * 8];
                #pragma unroll
                for (int dblk = 0; dblk < 4; dblk++) {
                    s16x8 vf = *(const s16x8*)&Vs[dblk * 32 + ql][ks * 16 + hf * 8];
                    out[dblk] = __builtin_amdgcn_mfma_f32_32x32x16_bf16(pf, vf, out[dblk], 0, 0, 0);
                }
            }
            __builtin_amdgcn_s_setprio(0);
        }
    }
    float linv = 1.0f / l_q;
    float inv[16];
    #pragma unroll
    for (int r = 0; r < 16; r++)
        inv[r] = __shfl(linv, (r & 3) + 8 * (r >> 2) + 4 * hf, 64);
    #pragma unroll
    for (int dblk = 0; dblk < 4; dblk++)
        #pragma unroll
        for (int r = 0; r < 16; r++) {
            int row = q0 + wave * 32 + (r & 3) + 8 * (r >> 2) + 4 * hf;
            attn[((size_t)(b * 2048) + row) * 2048 + h * 128 + dblk * 32 + ql] =
                f2bf(out[dblk][r] * inv[r]);
        }
}

extern "C" void kernel_launch(void* const* d_in, const int* in_sizes, int n_in,
                              void* d_out, int out_size, void* d_ws, size_t ws_size,
                              hipStream_t stream) {
    const float* x    = (const float*)d_in[0];
    const float* wq   = (const float*)d_in[1];
    const float* wk   = (const float*)d_in[2];
    const float* wv   = (const float*)d_in[3];
    const float* wo   = (const float*)d_in[4];
    const float* qg   = (const float*)d_in[5];
    const float* kg   = (const float*)d_in[6];
    const float* cosc = (const float*)d_in[7];
    const float* sinc = (const float*)d_in[8];

    char* ws = (char*)d_ws;
    unsigned short* xb   = (unsigned short*)(ws);                 // 16 MiB  x bf16 (4096x2048)
    unsigned short* w1t  = (unsigned short*)(ws + 16777216);      // 16 MiB  [wq|wk|wv]^T (4096x2048)
    unsigned short* w2t  = (unsigned short*)(ws + 33554432);      //  8 MiB  wo^T (2048x2048)
    unsigned short* qkv  = (unsigned short*)(ws + 41943040);      // 32 MiB  (4096x4096); dead after k_rms_rope
    unsigned short* Qt   = (unsigned short*)(ws + 75497472);      // 16 MiB  (2,16,2048,128)
    unsigned short* Kt   = (unsigned short*)(ws + 92274688);      //  8 MiB  (2,8,2048,128)
    unsigned short* Vt   = (unsigned short*)(ws + 100663296);     //  8 MiB  (2,8,2048,128)
    unsigned short* attn = (unsigned short*)(ws + 109051904);     // 16 MiB  (4096x2048)
    unsigned short* Vtg  = qkv;                                   //  8 MiB  (2,8,128,2048) reuses qkv

    k_convert_x<<<4096, 256, 0, stream>>>(x, xb, 8388608);
    k_transpose_w<<<dim3(64, 64), 256, 0, stream>>>(wq, w1t, 2048, 2048, 0, 2048);
    k_transpose_w<<<dim3(64, 32), 256, 0, stream>>>(wk, w1t, 2048, 1024, 2048, 2048);
    k_transpose_w<<<dim3(64, 32), 256, 0, stream>>>(wv, w1t, 2048, 1024, 3072, 2048);
    k_transpose_w<<<dim3(64, 64), 256, 0, stream>>>(wo, w2t, 2048, 2048, 0, 2048);
    k_gemm256<0><<<dim3(16, 16), 512, 0, stream>>>(xb, w1t, qkv, 4096, 4096, 2048);
    k_rms_rope<<<4096, 256, 0, stream>>>(qkv, qg, kg, cosc, sinc, Qt, Kt, Vt);
    k_transpose_v<<<dim3(64, 4, 16), 256, 0, stream>>>(Vt, Vtg);
    k_attn<<<512, 256, 0, stream>>>(Qt, Kt, Vtg, attn);
    k_gemm_bt<1><<<dim3(32, 16), 256, 0, stream>>>(attn, w2t, d_out, 4096, 2048, 2048);
}

// Round 13
// 226.798 us; speedup vs baseline: 1.1413x; 1.0098x over previous
//
#include <hip/hip_runtime.h>
#include <hip/hip_bf16.h>

// Problem constants: B=2, S=2048, DIM=2048, H=16, KVH=8, D=128

typedef __attribute__((ext_vector_type(8))) short s16x8;   // 8 bf16 in 4 VGPRs
typedef __attribute__((ext_vector_type(4))) float f32x4;
typedef __attribute__((ext_vector_type(16))) float f32x16;

typedef const __attribute__((address_space(1))) void* gas_t;
typedef __attribute__((address_space(3))) void* las_t;
#define GLL16(g, l) __builtin_amdgcn_global_load_lds((gas_t)(const void*)(g), (las_t)(void*)(l), 16, 0, 0)

static __device__ __forceinline__ unsigned short f2bf(float f) {
    union { float f; unsigned u; } v; v.f = f;
    unsigned r = v.u + 0x7FFF + ((v.u >> 16) & 1);   // RNE
    return (unsigned short)(r >> 16);
}
static __device__ __forceinline__ float bf2f(unsigned short h) {
    union { unsigned u; float f; } v; v.u = ((unsigned)h) << 16;
    return v.f;
}
static __device__ __forceinline__ float exp2_fast(float x) {
    float r; asm("v_exp_f32 %0, %1" : "=v"(r) : "v"(x)); return r;
}
static __device__ __forceinline__ unsigned cvt_pk_bf16(float a, float b) {
    unsigned r; asm("v_cvt_pk_bf16_f32 %0, %1, %2" : "=v"(r) : "v"(a), "v"(b)); return r;
}

// scale(1/sqrt(128)) * log2(e): baked into Q so softmax runs in exp2 domain
#define SCALE_L2E 0.12751744900929f

// ---------------- f32 -> bf16 elementwise convert (x) ----------------
__global__ __launch_bounds__(256) void k_convert_x(const float* __restrict__ x,
                                                   unsigned short* __restrict__ xb, int n) {
    int i = (blockIdx.x * 256 + threadIdx.x) * 8;
    if (i >= n) return;
    float4 a = *(const float4*)(x + i);
    float4 b = *(const float4*)(x + i + 4);
    s16x8 o;
    o[0] = (short)f2bf(a.x); o[1] = (short)f2bf(a.y); o[2] = (short)f2bf(a.z); o[3] = (short)f2bf(a.w);
    o[4] = (short)f2bf(b.x); o[5] = (short)f2bf(b.y); o[6] = (short)f2bf(b.z); o[7] = (short)f2bf(b.w);
    *(s16x8*)(xb + i) = o;
}

// ---------------- weight transpose f32 (K x N) -> bf16 (N x K) ----------------
__global__ __launch_bounds__(256) void k_transpose_w(const float* __restrict__ src,
                                                     unsigned short* __restrict__ dst,
                                                     int K, int N, int nbase, int dstld) {
    __shared__ float t[32][33];
    int k0 = blockIdx.x * 32, n0 = blockIdx.y * 32;
    int tx = threadIdx.x & 31, ty0 = threadIdx.x >> 5;
    for (int p = 0; p < 4; p++) {
        int ty = ty0 + p * 8;
        t[ty][tx] = src[(size_t)(k0 + ty) * N + n0 + tx];
    }
    __syncthreads();
    for (int p = 0; p < 4; p++) {
        int ty = ty0 + p * 8;
        dst[(size_t)(nbase + n0 + ty) * dstld + k0 + tx] = f2bf(t[tx][ty]);
    }
}

// ---------------- bf16 transpose: V (2048 x 128) -> Vt (128 x 2048), per (b,kvh) ----------------
__global__ __launch_bounds__(256) void k_transpose_v(const unsigned short* __restrict__ V,
                                                     unsigned short* __restrict__ Vt) {
    __shared__ unsigned short t[32][33];
    int s0 = blockIdx.x * 32, d0 = blockIdx.y * 32;
    size_t base = (size_t)blockIdx.z * 2048 * 128;
    int tx = threadIdx.x & 31, ty0 = threadIdx.x >> 5;
    for (int p = 0; p < 4; p++) {
        int ty = ty0 + p * 8;
        t[ty][tx] = V[base + (size_t)(s0 + ty) * 128 + d0 + tx];
    }
    __syncthreads();
    for (int p = 0; p < 4; p++) {
        int ty = ty0 + p * 8;
        Vt[base + (size_t)(d0 + ty) * 2048 + s0 + tx] = t[tx][ty];
    }
}

// ---------------- 256x256 GEMM v5: read-early phases + quad swizzle ----------------
// 512 thr (8 waves 2Mx4N). BK=64 as 4 pairs {A.kk0,B.kk0,A.kk1,B.kk1} of 256x32
// chunks (2 GLL each). Per phase: {ds_read frags, GLL issue, [vmcnt(4) at ph1/ph3],
// barrier, setprio(1), 16 MFMA, setprio(0), barrier} — ds_read latency hides under
// barrier-wait. vmcnt(4) at ph1 certifies this tile's kk1; at ph3 next tile's kk0.
// Quad swizzle (read col lg^((lr>>1)&3), source col (lane&3)^((lane>>3)&3)) spreads
// consecutive 8 lanes across all 8 LDS quads -> kills the 4-way in-group conflict.
template<int OUTF32>
__global__ __launch_bounds__(512, 2) void k_gemm256(const unsigned short* __restrict__ A,
                                                    const unsigned short* __restrict__ Bt,
                                                    void* __restrict__ Cout,
                                                    int M, int N, int K) {
    __shared__ unsigned short Ls[2][2][2][8192];   // [slot][mat A=0/B=1][kk][256*32] = 128 KiB
    int tid = threadIdx.x, lane = tid & 63, wave = tid >> 6;
    int wm = wave >> 2, wn = wave & 3;
    int lr = lane & 15, lg = lane >> 4;
    int swrow = wave * 16 + (lane >> 2);                   // staging row within 128-row half
    int scol  = (((lane & 3) ^ ((lane >> 3) & 3)) * 8);    // pre-swizzled source col (elems)
    int cg    = ((lg ^ ((lr >> 1) & 3)) * 8);              // swizzled read col (elems)
    const unsigned short* Ab = A  + (size_t)(blockIdx.x * 256) * K;
    const unsigned short* Bb = Bt + (size_t)(blockIdx.y * 256) * K;

    f32x4 acc[8][4] = {};
    int NK = K / 64;

    auto issue = [&](int slot, int mat, int kk, int k0) {
        const unsigned short* base = mat ? Bb : Ab;
        unsigned short* dst = &Ls[slot][mat][kk][wave * 512];
        GLL16(base + (size_t)swrow * K + k0 + kk * 32 + scol, dst);
        GLL16(base + (size_t)(swrow + 128) * K + k0 + kk * 32 + scol, dst + 4096);
    };

    // prologue: tile 0 fully staged, certify kk0 (retire oldest 2 pairs)
    issue(0, 0, 0, 0);
    issue(0, 1, 0, 0);
    issue(0, 0, 1, 0);
    issue(0, 1, 1, 0);
    asm volatile("s_waitcnt vmcnt(4)" ::: "memory");
    __builtin_amdgcn_s_barrier();

    for (int t = 0; t < NK; ++t) {
        int slot = t & 1, nslot = slot ^ 1;
        int kn = (t + 1) * 64;
        bool more = (t + 1) < NK;
        const unsigned short* As0 = Ls[slot][0][0];
        const unsigned short* Bs0 = Ls[slot][1][0];
        const unsigned short* As1 = Ls[slot][0][1];
        const unsigned short* Bs1 = Ls[slot][1][1];
        s16x8 af[4], bfr[4];

        // ---- phase 0: kk0, m0-3 (kk0 certified by prev tile's ph3 / prologue) ----
        #pragma unroll
        for (int m = 0; m < 4; m++) af[m]  = *(const s16x8*)&As0[(wm * 128 + m * 16 + lr) * 32 + cg];
        #pragma unroll
        for (int n = 0; n < 4; n++) bfr[n] = *(const s16x8*)&Bs0[(wn * 64 + n * 16 + lr) * 32 + cg];
        if (more) issue(nslot, 0, 0, kn);
        asm volatile("" ::: "memory");
        __builtin_amdgcn_s_barrier();
        __builtin_amdgcn_s_setprio(1);
        #pragma unroll
        for (int m = 0; m < 4; m++)
            #pragma unroll
            for (int n = 0; n < 4; n++)
                acc[m][n] = __builtin_amdgcn_mfma_f32_16x16x32_bf16(af[m], bfr[n], acc[m][n], 0, 0, 0);
        __builtin_amdgcn_s_setprio(0);
        asm volatile("" ::: "memory");
        __builtin_amdgcn_s_barrier();

        // ---- phase 1: kk0, m4-7 (bfr reused); vmcnt certifies this tile's kk1 ----
        #pragma unroll
        for (int m = 0; m < 4; m++) af[m] = *(const s16x8*)&As0[(wm * 128 + (m + 4) * 16 + lr) * 32 + cg];
        if (more) { issue(nslot, 1, 0, kn); asm volatile("s_waitcnt vmcnt(4)" ::: "memory"); }
        else      {                         asm volatile("s_waitcnt vmcnt(0)" ::: "memory"); }
        asm volatile("" ::: "memory");
        __builtin_amdgcn_s_barrier();
        __builtin_amdgcn_s_setprio(1);
        #pragma unroll
        for (int m = 0; m < 4; m++)
            #pragma unroll
            for (int n = 0; n < 4; n++)
                acc[m + 4][n] = __builtin_amdgcn_mfma_f32_16x16x32_bf16(af[m], bfr[n], acc[m + 4][n], 0, 0, 0);
        __builtin_amdgcn_s_setprio(0);
        asm volatile("" ::: "memory");
        __builtin_amdgcn_s_barrier();

        // ---- phase 2: kk1, m0-3 (kk1 certified by ph1) ----
        #pragma unroll
        for (int m = 0; m < 4; m++) af[m]  = *(const s16x8*)&As1[(wm * 128 + m * 16 + lr) * 32 + cg];
        #pragma unroll
        for (int n = 0; n < 4; n++) bfr[n] = *(const s16x8*)&Bs1[(wn * 64 + n * 16 + lr) * 32 + cg];
        if (more) issue(nslot, 0, 1, kn);
        asm volatile("" ::: "memory");
        __builtin_amdgcn_s_barrier();
        __builtin_amdgcn_s_setprio(1);
        #pragma unroll
        for (int m = 0; m < 4; m++)
            #pragma unroll
            for (int n = 0; n < 4; n++)
                acc[m][n] = __builtin_amdgcn_mfma_f32_16x16x32_bf16(af[m], bfr[n], acc[m][n], 0, 0, 0);
        __builtin_amdgcn_s_setprio(0);
        asm volatile("" ::: "memory");
        __builtin_amdgcn_s_barrier();

        // ---- phase 3: kk1, m4-7; vmcnt certifies next tile's kk0 ----
        #pragma unroll
        for (int m = 0; m < 4; m++) af[m] = *(const s16x8*)&As1[(wm * 128 + (m + 4) * 16 + lr) * 32 + cg];
        if (more) { issue(nslot, 1, 1, kn); asm volatile("s_waitcnt vmcnt(4)" ::: "memory"); }
        asm volatile("" ::: "memory");
        __builtin_amdgcn_s_barrier();
        __builtin_amdgcn_s_setprio(1);
        #pragma unroll
        for (int m = 0; m < 4; m++)
            #pragma unroll
            for (int n = 0; n < 4; n++)
                acc[m + 4][n] = __builtin_amdgcn_mfma_f32_16x16x32_bf16(af[m], bfr[n], acc[m + 4][n], 0, 0, 0);
        __builtin_amdgcn_s_setprio(0);
        asm volatile("" ::: "memory");
        __builtin_amdgcn_s_barrier();
    }

    int rbase = blockIdx.x * 256 + wm * 128;
    int cbase = blockIdx.y * 256 + wn * 64;
    #pragma unroll
    for (int am = 0; am < 8; am++)
        #pragma unroll
        for (int n = 0; n < 4; n++)
            #pragma unroll
            for (int r = 0; r < 4; r++) {
                int row = rbase + am * 16 + lg * 4 + r;
                int col = cbase + n * 16 + lr;
                float v = acc[am][n][r];
                if (OUTF32) ((float*)Cout)[(size_t)row * N + col] = v;
                else        ((unsigned short*)Cout)[(size_t)row * N + col] = f2bf(v);
            }
}

// ---------------- GEMM: 128x128 m97 structure (kept for gemm2, N=2048) ----------------
template<int OUTF32>
__global__ __launch_bounds__(256) void k_gemm_bt(const unsigned short* __restrict__ A,
                                                 const unsigned short* __restrict__ Bt,
                                                 void* __restrict__ Cout,
                                                 int M, int N, int K) {
    __shared__ unsigned short As[128 * 32];
    __shared__ unsigned short Bs[128 * 32];
    int tid = threadIdx.x;
    int lane = tid & 63;
    int wave = tid >> 6;
    int wm = wave >> 1, wn = wave & 1;
    int lr = lane & 15, lk = (lane >> 4) * 8;
    int srow = wave * 32 + (lane >> 2);
    int scol = (lane & 3) * 8;
    const unsigned short* Ag0 = A  + (size_t)(blockIdx.x * 128 + srow) * K + scol;
    const unsigned short* Ag1 = Ag0 + (size_t)16 * K;
    const unsigned short* Bg0 = Bt + (size_t)(blockIdx.y * 128 + srow) * K + scol;
    const unsigned short* Bg1 = Bg0 + (size_t)16 * K;
    unsigned short* Asw = &As[wave * 1024];
    unsigned short* Bsw = &Bs[wave * 1024];
    f32x4 acc[4][4] = {};
    for (int k0 = 0; k0 < K; k0 += 32) {
        __syncthreads();
        GLL16(Ag0 + k0, Asw);
        GLL16(Ag1 + k0, Asw + 512);
        GLL16(Bg0 + k0, Bsw);
        GLL16(Bg1 + k0, Bsw + 512);
        __syncthreads();
        s16x8 af[4], bfr[4];
        #pragma unroll
        for (int m = 0; m < 4; m++) af[m]  = *(const s16x8*)&As[(wm * 64 + m * 16 + lr) * 32 + lk];
        #pragma unroll
        for (int n = 0; n < 4; n++) bfr[n] = *(const s16x8*)&Bs[(wn * 64 + n * 16 + lr) * 32 + lk];
        #pragma unroll
        for (int m = 0; m < 4; m++)
            #pragma unroll
            for (int n = 0; n < 4; n++)
                acc[m][n] = __builtin_amdgcn_mfma_f32_16x16x32_bf16(af[m], bfr[n], acc[m][n], 0, 0, 0);
    }
    int rbase = blockIdx.x * 128 + wm * 64;
    int cbase = blockIdx.y * 128 + wn * 64;
    #pragma unroll
    for (int m = 0; m < 4; m++)
        #pragma unroll
        for (int n = 0; n < 4; n++)
            #pragma unroll
            for (int r = 0; r < 4; r++) {
                int row = rbase + m * 16 + (lane >> 4) * 4 + r;
                int col = cbase + n * 16 + lr;
                float v = acc[m][n][r];
                if (OUTF32) ((float*)Cout)[(size_t)row * N + col] = v;
                else        ((unsigned short*)Cout)[(size_t)row * N + col] = f2bf(v);
            }
}

// ---------------- fused RMSNorm + RoPE + head transpose (vectorized) ----------------
__global__ __launch_bounds__(256) void k_rms_rope(const unsigned short* __restrict__ qkv,
                                                  const float* __restrict__ qg,
                                                  const float* __restrict__ kg,
                                                  const float* __restrict__ cosc,
                                                  const float* __restrict__ sinc,
                                                  unsigned short* __restrict__ Qt,
                                                  unsigned short* __restrict__ Kt,
                                                  unsigned short* __restrict__ Vt) {
    int r = blockIdx.x;            // b*2048 + s
    int b = r >> 11;
    int s = r & 2047;
    int tid = threadIdx.x;
    int wave = tid >> 6, lane = tid & 63;
    int sl = lane >> 4;            // local segment 0..3
    int li = lane & 15;
    int d0 = li * 8;               // 0..120
    const unsigned short* row = qkv + (size_t)r * 4096;
    #pragma unroll
    for (int p = 0; p < 2; p++) {
        int seg = p * 16 + wave * 4 + sl;   // 0..31, wave-uniform type
        s16x8 raw = *(const s16x8*)(row + seg * 128 + d0);
        if (seg >= 24) {   // V: straight copy (wave-uniform branch)
            *(s16x8*)(Vt + ((size_t)(b * 8 + (seg - 24)) * 2048 + s) * 128 + d0) = raw;
            continue;
        }
        float e[8];
        #pragma unroll
        for (int j = 0; j < 8; j++) e[j] = bf2f((unsigned short)raw[j]);
        float ssq = 0.f;
        #pragma unroll
        for (int j = 0; j < 8; j++) ssq += e[j] * e[j];
        ssq += __shfl_xor(ssq, 1, 64);
        ssq += __shfl_xor(ssq, 2, 64);
        ssq += __shfl_xor(ssq, 4, 64);
        ssq += __shfl_xor(ssq, 8, 64);
        float rn = rsqrtf(ssq * (1.0f / 128.0f) + 1e-6f);
        const float* g = (seg < 16) ? qg : kg;
        float gs = (seg < 16) ? SCALE_L2E : 1.0f;
        float4 g0 = *(const float4*)(g + d0);
        float4 g1 = *(const float4*)(g + d0 + 4);
        float t[8];
        t[0] = e[0] * rn * g0.x * gs; t[1] = e[1] * rn * g0.y * gs;
        t[2] = e[2] * rn * g0.z * gs; t[3] = e[3] * rn * g0.w * gs;
        t[4] = e[4] * rn * g1.x * gs; t[5] = e[5] * rn * g1.y * gs;
        t[6] = e[6] * rn * g1.z * gs; t[7] = e[7] * rn * g1.w * gs;
        float pr[8];
        #pragma unroll
        for (int j = 0; j < 8; j++) pr[j] = __shfl_xor(t[j], 8, 64);
        int didx = d0 & 63;
        float4 c0 = *(const float4*)(cosc + (size_t)s * 64 + didx);
        float4 c1 = *(const float4*)(cosc + (size_t)s * 64 + didx + 4);
        float4 sn0 = *(const float4*)(sinc + (size_t)s * 64 + didx);
        float4 sn1 = *(const float4*)(sinc + (size_t)s * 64 + didx + 4);
        float cv[8] = {c0.x, c0.y, c0.z, c0.w, c1.x, c1.y, c1.z, c1.w};
        float sv[8] = {sn0.x, sn0.y, sn0.z, sn0.w, sn1.x, sn1.y, sn1.z, sn1.w};
        float sgn = (li < 8) ? -1.0f : 1.0f;
        s16x8 o;
        #pragma unroll
        for (int j = 0; j < 8; j++)
            o[j] = (short)f2bf(t[j] * cv[j] + sgn * pr[j] * sv[j]);
        unsigned short* dst = (seg < 16)
            ? Qt + ((size_t)(b * 16 + seg) * 2048 + s) * 128 + d0
            : Kt + ((size_t)(b * 8 + (seg - 16)) * 2048 + s) * 128 + d0;
        *(s16x8*)dst = o;
    }
}

// ---------------- causal GQA flash attention, 32x32 MFMA (unchanged from R11) ----------------
__global__ __launch_bounds__(256, 2) void k_attn(const unsigned short* __restrict__ Qt,
                                                 const unsigned short* __restrict__ Kt,
                                                 const unsigned short* __restrict__ Vtg,
                                                 unsigned short* __restrict__ attn) {
    __shared__ unsigned short Ks[64][136];     // K tile [kv][d], padded
    __shared__ unsigned short Vs[128][72];     // V^T tile [d][kv], padded
    __shared__ unsigned short Ps[4][32][72];   // per-wave P tile [q][kv], padded
    int bid = blockIdx.x;                  // 0..511
    int lo = bid & 255;
    int qb, bh;
    if (bid < 256) { qb = lo & 15;        bh = lo >> 4; }
    else           { qb = 15 - (lo & 15); bh = 16 + (lo >> 4); }
    int b = bh >> 4, h = bh & 15;
    int kvh = h >> 1;
    int tid = threadIdx.x;
    int lane = tid & 63, wave = tid >> 6;
    int ql = lane & 31;                    // q-local (wave's 32 rows)
    int hf = lane >> 5;                    // half 0/1
    int q0 = qb * 128;
    const unsigned short* Qb    = Qt + ((size_t)bh * 2048 + q0 + wave * 32 + ql) * 128;
    const unsigned short* Kbase = Kt + (size_t)(b * 8 + kvh) * 2048 * 128;
    const unsigned short* Vtb   = Vtg + (size_t)(b * 8 + kvh) * 128 * 2048;   // [d][s]
    s16x8 aq[8];
    #pragma unroll
    for (int ds = 0; ds < 8; ds++)
        aq[ds] = *(const s16x8*)(Qb + ds * 16 + hf * 8);
    f32x16 out[4] = {};
    float m_q = -1e30f, l_q = 0.f;
    int qglob = q0 + wave * 32 + ql;
    int qlo   = q0 + wave * 32;            // wave-uniform bounds
    int qhi   = qlo + 31;
    int ntiles = 2 * qb + 2;
    int krow = tid >> 4, kcol = (tid & 15) * 8;   // K: 16 rows x 128 cols per pass
    int vrow = tid >> 3, vcol = (tid & 7) * 8;    // V^T: 32 rows x 64 cols per pass
    s16x8 kpre[4], vpre[4];
    #pragma unroll
    for (int p = 0; p < 4; p++) {
        kpre[p] = *(const s16x8*)(Kbase + (size_t)(krow + p * 16) * 128 + kcol);
        vpre[p] = *(const s16x8*)(Vtb + (size_t)(vrow + p * 32) * 2048 + vcol);
    }

    for (int t = 0; t < ntiles; t++) {
        int k0 = t * 64;
        __syncthreads();   // previous tile's LDS reads complete
        #pragma unroll
        for (int p = 0; p < 4; p++) {
            *(s16x8*)&Ks[krow + p * 16][kcol] = kpre[p];
            *(s16x8*)&Vs[vrow + p * 32][vcol] = vpre[p];
        }
        __syncthreads();
        if (t + 1 < ntiles) {
            int kn = k0 + 64;
            #pragma unroll
            for (int p = 0; p < 4; p++) {
                kpre[p] = *(const s16x8*)(Kbase + (size_t)(kn + krow + p * 16) * 128 + kcol);
                vpre[p] = *(const s16x8*)(Vtb + (size_t)(vrow + p * 32) * 2048 + kn + vcol);
            }
        }
        if (k0 <= qhi) {
            f32x16 st[2] = {};
            __builtin_amdgcn_s_setprio(1);
            #pragma unroll
            for (int sub = 0; sub < 2; sub++)
                #pragma unroll
                for (int ds = 0; ds < 8; ds++) {
                    s16x8 kf = *(const s16x8*)&Ks[sub * 32 + ql][ds * 16 + hf * 8];
                    st[sub] = __builtin_amdgcn_mfma_f32_32x32x16_bf16(kf, aq[ds], st[sub], 0, 0, 0);
                }
            __builtin_amdgcn_s_setprio(0);
            float mx = -1e30f;
            if (k0 + 63 > qlo) {   // boundary tiles: apply causal mask
                #pragma unroll
                for (int sub = 0; sub < 2; sub++)
                    #pragma unroll
                    for (int r = 0; r < 16; r++) {
                        int kv = k0 + sub * 32 + (r & 3) + 8 * (r >> 2) + 4 * hf;
                        if (kv > qglob) st[sub][r] = -1e30f;
                        mx = fmaxf(mx, st[sub][r]);
                    }
            } else {
                #pragma unroll
                for (int sub = 0; sub < 2; sub++)
                    #pragma unroll
                    for (int r = 0; r < 16; r++) mx = fmaxf(mx, st[sub][r]);
            }
            mx = fmaxf(mx, __shfl_xor(mx, 32, 64));
            bool defer = __all(mx <= m_q + 8.0f);
            float sf = 1.0f;
            if (!defer) {
                float mnew = fmaxf(m_q, mx);
                sf = exp2_fast(m_q - mnew);
                m_q = mnew;
            }
            float rs = 0.f;
            #pragma unroll
            for (int sub = 0; sub < 2; sub++)
                #pragma unroll
                for (int r = 0; r < 16; r++) {
                    float e = exp2_fast(st[sub][r] - m_q);
                    st[sub][r] = e;
                    rs += e;
                }
            rs += __shfl_xor(rs, 32, 64);
            l_q = defer ? (l_q + rs) : (l_q * sf + rs);
            // pack P -> Ps[q][kv] via hardware cvt_pk (RNE)
            #pragma unroll
            for (int sub = 0; sub < 2; sub++)
                #pragma unroll
                for (int g = 0; g < 4; g++) {
                    uint2 w;
                    w.x = cvt_pk_bf16(st[sub][4 * g + 0], st[sub][4 * g + 1]);
                    w.y = cvt_pk_bf16(st[sub][4 * g + 2], st[sub][4 * g + 3]);
                    *(uint2*)&Ps[wave][ql][sub * 32 + g * 8 + hf * 4] = w;
                }
            if (!defer) {
                float sfr[16];
                #pragma unroll
                for (int r = 0; r < 16; r++)
                    sfr[r] = __shfl(sf, (r & 3) + 8 * (r >> 2) + 4 * hf, 64);
                #pragma unroll
                for (int dblk = 0; dblk < 4; dblk++)
                    #pragma unroll
                    for (int r = 0; r < 16; r++) out[dblk][r] *= sfr[r];
            }
            __builtin_amdgcn_s_setprio(1);
            #pragma unroll
            for (int ks = 0; ks < 4; ks++) {
                s16x8 pf = *(const s16x8*)&Ps[wave][ql][ks * 16 + hf * 8];
                #pragma unroll
                for (int dblk = 0; dblk < 4; dblk++) {
                    s16x8 vf = *(const s16x8*)&Vs[dblk * 32 + ql][ks * 16 + hf * 8];
                    out[dblk] = __builtin_amdgcn_mfma_f32_32x32x16_bf16(pf, vf, out[dblk], 0, 0, 0);
                }
            }
            __builtin_amdgcn_s_setprio(0);
        }
    }
    float linv = 1.0f / l_q;
    float inv[16];
    #pragma unroll
    for (int r = 0; r < 16; r++)
        inv[r] = __shfl(linv, (r & 3) + 8 * (r >> 2) + 4 * hf, 64);
    #pragma unroll
    for (int dblk = 0; dblk < 4; dblk++)
        #pragma unroll
        for (int r = 0; r < 16; r++) {
            int row = q0 + wave * 32 + (r & 3) + 8 * (r >> 2) + 4 * hf;
            attn[((size_t)(b * 2048) + row) * 2048 + h * 128 + dblk * 32 + ql] =
                f2bf(out[dblk][r] * inv[r]);
        }
}

extern "C" void kernel_launch(void* const* d_in, const int* in_sizes, int n_in,
                              void* d_out, int out_size, void* d_ws, size_t ws_size,
                              hipStream_t stream) {
    const float* x    = (const float*)d_in[0];
    const float* wq   = (const float*)d_in[1];
    const float* wk   = (const float*)d_in[2];
    const float* wv   = (const float*)d_in[3];
    const float* wo   = (const float*)d_in[4];
    const float* qg   = (const float*)d_in[5];
    const float* kg   = (const float*)d_in[6];
    const float* cosc = (const float*)d_in[7];
    const float* sinc = (const float*)d_in[8];

    char* ws = (char*)d_ws;
    unsigned short* xb   = (unsigned short*)(ws);                 // 16 MiB  x bf16 (4096x2048)
    unsigned short* w1t  = (unsigned short*)(ws + 16777216);      // 16 MiB  [wq|wk|wv]^T (4096x2048)
    unsigned short* w2t  = (unsigned short*)(ws + 33554432);      //  8 MiB  wo^T (2048x2048)
    unsigned short* qkv  = (unsigned short*)(ws + 41943040);      // 32 MiB  (4096x4096); dead after k_rms_rope
    unsigned short* Qt   = (unsigned short*)(ws + 75497472);      // 16 MiB  (2,16,2048,128)
    unsigned short* Kt   = (unsigned short*)(ws + 92274688);      //  8 MiB  (2,8,2048,128)
    unsigned short* Vt   = (unsigned short*)(ws + 100663296);     //  8 MiB  (2,8,2048,128)
    unsigned short* attn = (unsigned short*)(ws + 109051904);     // 16 MiB  (4096x2048)
    unsigned short* Vtg  = qkv;                                   //  8 MiB  (2,8,128,2048) reuses qkv

    k_convert_x<<<4096, 256, 0, stream>>>(x, xb, 8388608);
    k_transpose_w<<<dim3(64, 64), 256, 0, stream>>>(wq, w1t, 2048, 2048, 0, 2048);
    k_transpose_w<<<dim3(64, 32), 256, 0, stream>>>(wk, w1t, 2048, 1024, 2048, 2048);
    k_transpose_w<<<dim3(64, 32), 256, 0, stream>>>(wv, w1t, 2048, 1024, 3072, 2048);
    k_transpose_w<<<dim3(64, 64), 256, 0, stream>>>(wo, w2t, 2048, 2048, 0, 2048);
    k_gemm256<0><<<dim3(16, 16), 512, 0, stream>>>(xb, w1t, qkv, 4096, 4096, 2048);
    k_rms_rope<<<4096, 256, 0, stream>>>(qkv, qg, kg, cosc, sinc, Qt, Kt, Vt);
    k_transpose_v<<<dim3(64, 4, 16), 256, 0, stream>>>(Vt, Vtg);
    k_attn<<<512, 256, 0, stream>>>(Qt, Kt, Vtg, attn);
    k_gemm_bt<1><<<dim3(32, 16), 256, 0, stream>>>(attn, w2t, d_out, 4096, 2048, 2048);
}